// Round 5
// baseline (531.104 us; speedup 1.0000x reference)
//
#include <hip/hip_runtime.h>

// EdgeConvEncoder R13 (on R12):
//  - edge_attn: ISA-forced load cluster. R12 showed pre-RA sched_barrier is
//    undone by the register allocator (rematerializes restrict loads at uses;
//    VGPR stayed 32). Now: 12x asm-volatile global_load_dwordx4 (real VGPR
//    quad outputs, fixed order) + counted s_waitcnt vmcnt(4) tying q/k quads
//    before softmax (v still in flight) + vmcnt(0) tying v before PV.
//    LB(512,6) gives the ~72-reg peak headroom (occupancy was already
//    3 blocks/CU).

typedef short bf16x8 __attribute__((ext_vector_type(8)));
typedef unsigned int u32x4 __attribute__((ext_vector_type(4)));
typedef float f32x4 __attribute__((ext_vector_type(4)));
typedef float f32x2 __attribute__((ext_vector_type(2)));

__device__ __forceinline__ unsigned short f2bf(float f) {
  unsigned int u = __float_as_uint(f);
  u += 0x7FFFu + ((u >> 16) & 1u);  // round-to-nearest-even
  return (unsigned short)(u >> 16);
}
__device__ __forceinline__ float b2f(short s) {
  return __uint_as_float(((unsigned)(unsigned short)s) << 16);
}
// unpack a dword holding 2 bf16 -> f32x2 {lo, hi}
__device__ __forceinline__ f32x2 bfpair(unsigned w) {
  f32x2 r;
  r.x = __uint_as_float(w << 16);
  r.y = __uint_as_float(w & 0xffff0000u);
  return r;
}
// ISA-level 16B gather: order-fixed, dest quad is a hard register obligation
__device__ __forceinline__ u32x4 gload16(const void* p) {
  u32x4 r;
  asm volatile("global_load_dwordx4 %0, %1, off" : "=v"(r) : "v"(p));
  return r;
}

// ---------------- weight packing: 6 matrices (W1=top-bot x3, W2=bot x3) ----
__device__ __forceinline__ void pack_w_seg(const float* __restrict__ wq,
                                           const float* __restrict__ wk,
                                           const float* __restrict__ wv,
                                           unsigned short* __restrict__ dst,
                                           int IN, int O, float kscale, int id) {
  int kchunks = IN >> 5, nchunks = O >> 4;
  int total = 6 * nchunks * kchunks * 64;
  if (id >= total) return;
  int lane = id & 63;
  int frag = id >> 6;
  int kc = frag % kchunks;
  int nc = (frag / kchunks) % nchunks;
  int mat = frag / (kchunks * nchunks);
  const float* w = (mat % 3 == 0) ? wq : (mat % 3 == 1) ? wk : wv;
  float mul = (mat % 3 == 1) ? kscale : 1.0f;
  int n = nc * 16 + (lane & 15);
  int k0 = kc * 32 + (lane >> 4) * 8;
  unsigned short tmp[8];
#pragma unroll
  for (int j = 0; j < 8; ++j) {
    int row = k0 + j;
    float bot = w[(size_t)(IN + row) * O + n];
    float val = (mat < 3) ? (w[(size_t)row * O + n] - bot) : bot;
    tmp[j] = f2bf(val * mul);
  }
  uint4 o;
  o.x = (unsigned)tmp[0] | ((unsigned)tmp[1] << 16);
  o.y = (unsigned)tmp[2] | ((unsigned)tmp[3] << 16);
  o.z = (unsigned)tmp[4] | ((unsigned)tmp[5] << 16);
  o.w = (unsigned)tmp[6] | ((unsigned)tmp[7] << 16);
  reinterpret_cast<uint4*>(dst)[id] = o;
}

__device__ __forceinline__ void pack_b_seg(const float* __restrict__ bq,
                                           const float* __restrict__ bk,
                                           const float* __restrict__ bv, float kscale, int O,
                                           float* __restrict__ out, int i) {
  int mat = i / O, c = i % O;
  float v = 0.f;
  if (mat == 0) v = bq[c];
  else if (mat == 1) v = bk[c] * kscale;
  else if (mat == 2) v = bv[c];
  out[i] = v;
}

// ---------------- fused preprocessing ----------------
// zeros (hist, s0+s1, d_out) + weight pack + bias pack + x f32->bf16
__global__ void preproc(
    uint4* __restrict__ z0, int n0, uint4* __restrict__ z1, int n1,
    uint4* __restrict__ z2, int n2,
    const float* __restrict__ x, unsigned short* __restrict__ xb, int n8,
    const float* __restrict__ wq0, const float* __restrict__ wk0, const float* __restrict__ wv0,
    const float* __restrict__ wq1, const float* __restrict__ wk1, const float* __restrict__ wv1,
    const float* __restrict__ wq2, const float* __restrict__ wk2, const float* __restrict__ wv2,
    unsigned short* __restrict__ wp0, unsigned short* __restrict__ wp1,
    unsigned short* __restrict__ wp2,
    const float* __restrict__ bq0, const float* __restrict__ bk0, const float* __restrict__ bv0,
    const float* __restrict__ bq1, const float* __restrict__ bk1, const float* __restrict__ bv1,
    const float* __restrict__ bq2, const float* __restrict__ bk2, const float* __restrict__ bv2,
    float* __restrict__ bias0, float* __restrict__ bias1, float* __restrict__ bias2,
    float sc16, float sc8) {
  const int tid = blockIdx.x * blockDim.x + threadIdx.x;
  const int stride = gridDim.x * blockDim.x;
  const uint4 Z = make_uint4(0u, 0u, 0u, 0u);
  for (int j = tid; j < n0; j += stride) z0[j] = Z;
  for (int j = tid; j < n1; j += stride) z1[j] = Z;
  for (int j = tid; j < n2; j += stride) z2[j] = Z;
  for (int j = tid; j < n8; j += stride) {
    float4 a = reinterpret_cast<const float4*>(x)[2 * j];
    float4 b = reinterpret_cast<const float4*>(x)[2 * j + 1];
    uint4 o;
    o.x = (unsigned)f2bf(a.x) | ((unsigned)f2bf(a.y) << 16);
    o.y = (unsigned)f2bf(a.z) | ((unsigned)f2bf(a.w) << 16);
    o.z = (unsigned)f2bf(b.x) | ((unsigned)f2bf(b.y) << 16);
    o.w = (unsigned)f2bf(b.z) | ((unsigned)f2bf(b.w) << 16);
    reinterpret_cast<uint4*>(xb)[j] = o;
  }
  if (tid < 12288) pack_w_seg(wq0, wk0, wv0, wp0, 128, 128, sc16, tid);
  else if (tid < 18432) pack_w_seg(wq1, wk1, wv1, wp1, 128, 64, sc8, tid - 12288);
  else if (tid < 24576) pack_w_seg(wq2, wk2, wv2, wp2, 64, 128, sc16, tid - 18432);
  else if (tid < 24576 + 1920) {
    int i = tid - 24576;
    if (i < 768) pack_b_seg(bq0, bk0, bv0, sc16, 128, bias0, i);
    else if (i < 1152) pack_b_seg(bq1, bk1, bv1, sc8, 64, bias1, i - 768);
    else pack_b_seg(bq2, bk2, bv2, sc16, 128, bias2, i - 1152);
  }
}

// ---------------- counting sort by dst ----------------
__global__ void hist3(const int* __restrict__ e0, const int* __restrict__ e1,
                      const int* __restrict__ e2, int E, int* __restrict__ hist,
                      int* __restrict__ rank, int NP) {
  int i = blockIdx.x * blockDim.x + threadIdx.x;
  if (i >= E) return;
  rank[0 * E + i] = atomicAdd(&hist[0 * NP + e0[E + i]], 1);
  rank[1 * E + i] = atomicAdd(&hist[1 * NP + e1[E + i]], 1);
  rank[2 * E + i] = atomicAdd(&hist[2 * NP + e2[E + i]], 1);
}

__device__ __forceinline__ int block_scan_excl256(int v, int* buf, int t, int* total) {
  buf[t] = v;
  __syncthreads();
#pragma unroll
  for (int off = 1; off < 256; off <<= 1) {
    int add = (t >= off) ? buf[t - off] : 0;
    __syncthreads();
    buf[t] += add;
    __syncthreads();
  }
  int incl = buf[t];
  *total = buf[255];
  __syncthreads();
  return incl - v;
}

__global__ void scan_pass1(const int* __restrict__ hist, int* __restrict__ excl,
                           int* __restrict__ bsum, int n, int NP) {
  __shared__ int buf[256];
  int y = blockIdx.y, t = threadIdx.x;
  int i = blockIdx.x * 256 + t;
  int v = (i < n) ? hist[y * NP + i] : 0;
  int total;
  int ex = block_scan_excl256(v, buf, t, &total);
  if (i < NP) excl[y * NP + i] = ex;
  if (t == 0) bsum[y * 256 + blockIdx.x] = total;
}

__global__ void scan_pass2(int* __restrict__ bsum, int nblk) {
  __shared__ int buf[256];
  int y = blockIdx.y, t = threadIdx.x;
  int v = (t < nblk) ? bsum[y * 256 + t] : 0;
  int total;
  int ex = block_scan_excl256(v, buf, t, &total);
  bsum[y * 256 + t] = ex;
}

__global__ void scan_pass3(const int* __restrict__ excl, const int* __restrict__ bsum,
                           int* __restrict__ rowptr, int n, int NP, int RP, int E) {
  int y = blockIdx.y;
  int i = blockIdx.x * 256 + threadIdx.x;
  if (i < n) rowptr[y * RP + i] = excl[y * NP + i] + bsum[y * 256 + blockIdx.x];
  if (i == 0) rowptr[y * RP + n] = E;
}

// scatter: pos = rowptr[d] + rank (no atomics); nontemporal 8B store
__global__ void scatter3(const int* __restrict__ e0, const int* __restrict__ e1,
                         const int* __restrict__ e2, int E, const int* __restrict__ rowptr,
                         const int* __restrict__ rank, long long* __restrict__ pairs,
                         int NP, int RP) {
  int y = blockIdx.y;
  const int* e = (y == 0) ? e0 : (y == 1) ? e1 : e2;
  int i = blockIdx.x * 256 + threadIdx.x;
  if (i >= E) return;
  int sN = e[i], d = e[E + i];
  int pos = rowptr[y * RP + d] + rank[(size_t)y * E + i];
  long long val = ((long long)(unsigned)d << 32) | (unsigned)sN;  // x=sN, y=d
  __builtin_nontemporal_store(val, &pairs[(size_t)y * E + pos]);
}

// ---------------- node-level GEMM ----------------
// 1-D padded grid, bijective XCD swizzle; logical lb -> (tile = lb/G, grp = lb%G)
// so the G column-group blocks for one xb tile are consecutive on one XCD.
template <int IN, int O, int G>
__global__ __launch_bounds__(256, 4) void node_gemm(
    const unsigned short* __restrict__ xb, int N, int NT,
    const unsigned short* __restrict__ wpack, const float* __restrict__ bias6,
    unsigned short* __restrict__ Y1, unsigned short* __restrict__ Y2) {
  constexpr int KC = IN / 32;
  constexpr int NCH = O / 16;
  constexpr int CHR = IN / 8;
  constexpr int CM = CHR - 1;
  __shared__ unsigned short tiles[64 * IN];

  const int chunk = gridDim.x >> 3;  // grid is a multiple of 8
  const int lb = (blockIdx.x & 7) * chunk + (blockIdx.x >> 3);
  if (lb >= NT * G) return;
  const int tile = lb / G;
  const int grp = lb % G;

  const int t = threadIdx.x, w = t >> 6, ln = t & 63;
  const int n0 = tile * 64;

  {
    constexpr int RPI = 64 / CHR;
    constexpr int NI = 16 / RPI;
    const int r_in = ln / CHR, c = ln % CHR;
#pragma unroll
    for (int i = 0; i < NI; ++i) {
      int row = w * 16 + i * RPI + r_in;
      int node = min(n0 + row, N - 1);
      int sc = c ^ (row & CM);
      const unsigned short* g = xb + (size_t)node * IN + sc * 8;
      unsigned short* l = &tiles[(size_t)(w * 16 + i * RPI) * IN];
      __builtin_amdgcn_global_load_lds(
          (const __attribute__((address_space(1))) unsigned int*)g,
          (__attribute__((address_space(3))) unsigned int*)l, 16, 0, 0);
    }
  }
  __syncthreads();

  const int col = ln & 15, quad = ln >> 4;
  const int g0 = grp * 8 + w * 2;

  f32x4 acc[2][4];
#pragma unroll
  for (int cc = 0; cc < 2; ++cc)
#pragma unroll
    for (int m = 0; m < 4; ++m) acc[cc][m] = (f32x4){0.f, 0.f, 0.f, 0.f};

#pragma unroll
  for (int kc = 0; kc < KC; ++kc) {
    bf16x8 a[4];
#pragma unroll
    for (int m = 0; m < 4; ++m) {
      int row = m * 16 + col;
      int sc = (kc * 4 + quad) ^ (row & CM);
      a[m] = *reinterpret_cast<const bf16x8*>(&tiles[(size_t)row * IN + sc * 8]);
    }
#pragma unroll
    for (int cc = 0; cc < 2; ++cc) {
      const bf16x8 b = *reinterpret_cast<const bf16x8*>(
          wpack + ((size_t)((g0 + cc) * KC + kc) * 64 + ln) * 8);
#pragma unroll
      for (int m = 0; m < 4; ++m)
        acc[cc][m] = __builtin_amdgcn_mfma_f32_16x16x32_bf16(a[m], b, acc[cc][m], 0, 0, 0);
    }
  }

#pragma unroll
  for (int cc = 0; cc < 2; ++cc) {
    int gch = g0 + cc;
    int mat = gch / NCH, ncg = gch % NCH;
    unsigned short* Yp = (mat < 3) ? Y1 : Y2;
    int mo = (mat < 3) ? mat : mat - 3;
    float bv = bias6[gch * 16 + col];
    size_t coloff = (size_t)mo * O + ncg * 16 + col;
#pragma unroll
    for (int m = 0; m < 4; ++m)
#pragma unroll
      for (int r = 0; r < 4; ++r) {
        int node = n0 + m * 16 + quad * 4 + r;
        if (node < N) Yp[(size_t)node * (3 * O) + coloff] = f2bf(acc[cc][m][r] + bv);
      }
  }
}

// ---------------- gather-based edge kernel ----------------
// 512 threads, 64 edges, 8 threads/edge, thread = one head (HS channels).
// 12 asm global_load_dwordx4 (order-fixed, register-resident) + counted
// s_waitcnt vmcnt(N): softmax starts with v-loads still in flight.
template <int O, int HS>
__global__ __launch_bounds__(512, 6) void edge_attn_kernel(
    const unsigned short* __restrict__ Y1, const unsigned short* __restrict__ Y2,
    const int2* __restrict__ pairs, const int E, float* __restrict__ s) {
  constexpr int NL = HS / 8;
  constexpr int PM = O / 4 - 1;
  __shared__ float ctx[64 * O];
  __shared__ int dstL[64];

  const int chunkB = gridDim.x >> 3;
  const int lb = (blockIdx.x & 7) * chunkB + (blockIdx.x >> 3);
  if (lb * 64 >= E) return;

  const int t = threadIdx.x;
  const int e = t >> 3, head = t & 7;
  const int eG = lb * 64 + e;
  const int eC = min(eG, E - 1);
  const bool valid = eG < E;
  const int2 p = pairs[eC];
  const int sN = p.x, dN = p.y;
  if ((t & 7) == 0) dstL[e] = dN;
  const float dd = fabsf((float)(dN - sN));
  const float ew = (dd > 8.f) ? 1.f : ((dd == 8.f) ? 0.f : -1.f);

  const unsigned short* b1 = Y1 + (size_t)dN * (3 * O) + head * HS;
  const unsigned short* b2 = Y2 + (size_t)sN * (3 * O) + head * HS;

  // ---- forced full-width load cluster (issue order: q1 q2 k1 k2 v1 v2) ----
  u32x4 q1[NL], q2[NL], k1[NL], k2[NL], v1[NL], v2[NL];
#pragma unroll
  for (int l = 0; l < NL; ++l) q1[l] = gload16(b1 + l * 8);
#pragma unroll
  for (int l = 0; l < NL; ++l) q2[l] = gload16(b2 + l * 8);
#pragma unroll
  for (int l = 0; l < NL; ++l) k1[l] = gload16(b1 + O + l * 8);
#pragma unroll
  for (int l = 0; l < NL; ++l) k2[l] = gload16(b2 + O + l * 8);
#pragma unroll
  for (int l = 0; l < NL; ++l) v1[l] = gload16(b1 + 2 * O + l * 8);
#pragma unroll
  for (int l = 0; l < NL; ++l) v2[l] = gload16(b2 + 2 * O + l * 8);

  // wait for q/k (8 oldest for NL=2; 4 oldest for NL=1) -> v still in flight
  if constexpr (NL == 2) {
    asm volatile("s_waitcnt vmcnt(4)"
                 : "+v"(q1[0]), "+v"(q1[1]), "+v"(q2[0]), "+v"(q2[1]),
                   "+v"(k1[0]), "+v"(k1[1]), "+v"(k2[0]), "+v"(k2[1]));
  } else {
    asm volatile("s_waitcnt vmcnt(2)"
                 : "+v"(q1[0]), "+v"(q2[0]), "+v"(k1[0]), "+v"(k2[0]));
  }
  __builtin_amdgcn_sched_barrier(0);

  f32x2 ex2[NL * 4];
  f32x2 sum2 = (f32x2){0.f, 0.f};
#pragma unroll
  for (int l = 0; l < NL; ++l)
#pragma unroll
    for (int d = 0; d < 4; ++d) {
      f32x2 q = bfpair(q1[l][d]) + bfpair(q2[l][d]);
      f32x2 k = bfpair(k1[l][d]) + bfpair(k2[l][d]);
      f32x2 qk = q * k;  // log2e already folded into k
      f32x2 eo;
      eo.x = exp2f(qk.x);
      eo.y = exp2f(qk.y);
      ex2[l * 4 + d] = eo;
      sum2 += eo;
    }
  const float sum = sum2.x + sum2.y;
  const float rs = valid ? (ew / sum) : 0.f;
  const f32x2 rs2 = (f32x2){rs, rs};

  // wait for v
  if constexpr (NL == 2) {
    asm volatile("s_waitcnt vmcnt(0)"
                 : "+v"(v1[0]), "+v"(v1[1]), "+v"(v2[0]), "+v"(v2[1]));
  } else {
    asm volatile("s_waitcnt vmcnt(0)" : "+v"(v1[0]), "+v"(v2[0]));
  }
  __builtin_amdgcn_sched_barrier(0);

#pragma unroll
  for (int l = 0; l < NL; ++l) {
#pragma unroll
    for (int g2 = 0; g2 < 2; ++g2) {
      f32x2 oa = ex2[l * 4 + g2 * 2] * rs2 * (bfpair(v1[l][g2 * 2]) + bfpair(v2[l][g2 * 2]));
      f32x2 ob = ex2[l * 4 + g2 * 2 + 1] * rs2 *
                 (bfpair(v1[l][g2 * 2 + 1]) + bfpair(v2[l][g2 * 2 + 1]));
      f32x4 o = (f32x4){oa.x, oa.y, ob.x, ob.y};
      int g = l * 2 + g2;
      int pch = (g * 8 + head + e) & PM;
      *reinterpret_cast<f32x4*>(&ctx[e * O + pch * 4]) = o;
    }
  }
  __syncthreads();

  {
    constexpr int GRP = 512 / O;
    constexpr int EPT = 64 / GRP;
    const int hs2 = t & 7;
    const int cs = (t >> 3) & (HS - 1);
    const int colA = hs2 * HS + cs;
    const int seg0 = (t / O) * EPT;
    const int inv = (cs >> 2) * 8 + hs2;
    const int js = cs & 3;
    float run = 0.f;
    int runstart = 0;           // i where current run began (0 => may predate segment)
    int dcur = dstL[seg0];
#pragma unroll
    for (int i = 0; i < EPT; ++i) {
      int ee = seg0 + i;
      int pch = (inv + ee) & PM;
      run += ctx[ee * O + pch * 4 + js];
      int dnext = (i < EPT - 1) ? dstL[ee + 1] : -1;
      if (dnext != dcur) {
        float* addr = &s[(size_t)dcur * O + colA];
        // run fully contained in this thread's segment -> exclusive -> plain store
        if (runstart > 0 && i < EPT - 1) *addr = run;
        else atomicAdd(addr, run);
        run = 0.f;
        runstart = i + 1;
        dcur = dnext;
      }
    }
  }
}

// ---------------- finalize ----------------
__global__ void finalize_relu_f32bf16(float* __restrict__ s, const int* __restrict__ rowptr,
                                      unsigned short* __restrict__ xbo, int total4, int Odiv4) {
  int i = blockIdx.x * blockDim.x + threadIdx.x;
  if (i >= total4) return;
  int node = i / Odiv4;
  float c = fmaxf((float)(rowptr[node + 1] - rowptr[node]), 1.0f);
  float4 v = reinterpret_cast<float4*>(s)[i];
  v.x = fmaxf(v.x / c, 0.f);
  v.y = fmaxf(v.y / c, 0.f);
  v.z = fmaxf(v.z / c, 0.f);
  v.w = fmaxf(v.w / c, 0.f);
  reinterpret_cast<float4*>(s)[i] = v;
  ushort4 o = make_ushort4(f2bf(v.x), f2bf(v.y), f2bf(v.z), f2bf(v.w));
  reinterpret_cast<ushort4*>(xbo)[i] = o;
}

__global__ void finalize_relu_bf16(const float* __restrict__ s, const int* __restrict__ rowptr,
                                   unsigned short* __restrict__ xbo, int total4, int Odiv4) {
  int i = blockIdx.x * blockDim.x + threadIdx.x;
  if (i >= total4) return;
  int node = i / Odiv4;
  float c = fmaxf((float)(rowptr[node + 1] - rowptr[node]), 1.0f);
  float4 v = reinterpret_cast<const float4*>(s)[i];
  ushort4 o = make_ushort4(f2bf(fmaxf(v.x / c, 0.f)), f2bf(fmaxf(v.y / c, 0.f)),
                           f2bf(fmaxf(v.z / c, 0.f)), f2bf(fmaxf(v.w / c, 0.f)));
  reinterpret_cast<ushort4*>(xbo)[i] = o;
}

__global__ void finalize_add_relu(float* __restrict__ out, const float* __restrict__ x0,
                                  const int* __restrict__ rowptr, int total4, int Odiv4) {
  int i = blockIdx.x * blockDim.x + threadIdx.x;
  if (i >= total4) return;
  int node = i / Odiv4;
  float c = fmaxf((float)(rowptr[node + 1] - rowptr[node]), 1.0f);
  float4 v = reinterpret_cast<float4*>(out)[i];
  float4 r = reinterpret_cast<const float4*>(x0)[i];
  v.x = fmaxf(v.x / c + r.x, 0.f);
  v.y = fmaxf(v.y / c + r.y, 0.f);
  v.z = fmaxf(v.z / c + r.z, 0.f);
  v.w = fmaxf(v.w / c + r.w, 0.f);
  reinterpret_cast<float4*>(out)[i] = v;
}

extern "C" void kernel_launch(void* const* d_in, const int* in_sizes, int n_in,
                              void* d_out, int out_size, void* d_ws, size_t ws_size,
                              hipStream_t stream) {
  const float* x = (const float*)d_in[0];
  const int* e0 = (const int*)d_in[1];
  const int* e1 = (const int*)d_in[2];
  const int* e2 = (const int*)d_in[3];
  const float* wq0 = (const float*)d_in[5];
  const float* bq0 = (const float*)d_in[6];
  const float* wk0 = (const float*)d_in[7];
  const float* bk0 = (const float*)d_in[8];
  const float* wv0 = (const float*)d_in[9];
  const float* bv0 = (const float*)d_in[10];
  const float* wq1 = (const float*)d_in[11];
  const float* bq1 = (const float*)d_in[12];
  const float* wk1 = (const float*)d_in[13];
  const float* bk1 = (const float*)d_in[14];
  const float* wv1 = (const float*)d_in[15];
  const float* bv1 = (const float*)d_in[16];
  const float* wq2 = (const float*)d_in[17];
  const float* bq2 = (const float*)d_in[18];
  const float* wk2 = (const float*)d_in[19];
  const float* bk2 = (const float*)d_in[20];
  const float* wv2 = (const float*)d_in[21];
  const float* bv2 = (const float*)d_in[22];

  const int N = in_sizes[0] / 128;  // 50000
  const int E = in_sizes[1] / 2;    // 500000
  const int NBLK = (N + 255) / 256;
  const int NP = NBLK * 256;
  const int RP = NP + 256;
  const float LOG2E = 1.4426950408889634f;
  const float SC16 = 0.25f * LOG2E;                 // 1/sqrt(16) * log2e
  const float SC8 = 0.35355339059327373f * LOG2E;   // 1/sqrt(8)  * log2e

  // ---- workspace carve-up ----
  unsigned short* wp0 = (unsigned short*)d_ws;       // 98304 shorts
  unsigned short* wp1 = wp0 + 98304;                 // 49152
  unsigned short* wp2 = wp1 + 49152;                 // 49152
  float* bias0 = (float*)(wp2 + 49152);              // 768
  float* bias1 = bias0 + 768;                        // 384
  float* bias2 = bias1 + 384;                        // 768
  unsigned short* xb = (unsigned short*)(bias2 + 768);  // N*128
  unsigned short* Y1 = xb + (size_t)N * 128;         // N*384
  unsigned short* Y2 = Y1 + (size_t)N * 384;         // N*384
  float* s0 = (float*)(Y2 + (size_t)N * 384);        // N*128
  float* s1 = s0 + (size_t)N * 128;                  // N*64
  int* hist = (int*)(s1 + (size_t)N * 64);           // 3*NP
  int* excl = hist + 3 * (size_t)NP;                 // 3*NP
  int* bsum = excl + 3 * (size_t)NP;                 // 768
  int* rowptr = bsum + 768;                          // 3*RP
  int* rank = rowptr + 3 * (size_t)RP;               // 3*E
  long long* pairs = (long long*)(rank + 3 * (size_t)E + 2);  // 3*E (8B aligned)

  // fused preprocessing: zeros + weight/bias pack + x->bf16
  preproc<<<2048, 256, 0, stream>>>(
      (uint4*)hist, 3 * NP / 4, (uint4*)s0, N * 48, (uint4*)d_out, out_size / 4,
      x, xb, N * 16,
      wq0, wk0, wv0, wq1, wk1, wv1, wq2, wk2, wv2, wp0, wp1, wp2,
      bq0, bk0, bv0, bq1, bk1, bv1, bq2, bk2, bv2, bias0, bias1, bias2,
      SC16, SC8);

  const int EB256 = (E + 255) / 256;
  hist3<<<EB256, 256, 0, stream>>>(e0, e1, e2, E, hist, rank, NP);
  scan_pass1<<<dim3(NBLK, 3), 256, 0, stream>>>(hist, excl, bsum, N, NP);
  scan_pass2<<<dim3(1, 3), 256, 0, stream>>>(bsum, NBLK);
  scan_pass3<<<dim3(NBLK, 3), 256, 0, stream>>>(excl, bsum, rowptr, N, NP, RP, E);
  scatter3<<<dim3(EB256, 3), 256, 0, stream>>>(e0, e1, e2, E, rowptr, rank, pairs, NP, RP);

  const int NT = (N + 63) / 64;
  const int EBK = (E + 63) / 64;
  const int EGRID = 8 * ((EBK + 7) / 8);  // bijective XCD swizzle grid
  const int GG6 = 8 * ((NT * 6 + 7) / 8);
  const int GG3 = 8 * ((NT * 3 + 7) / 8);

  // Layer 0: IN=128, O=128, HS=16
  node_gemm<128, 128, 6><<<GG6, 256, 0, stream>>>(xb, N, NT, wp0, bias0, Y1, Y2);
  edge_attn_kernel<128, 16><<<EGRID, 512, 0, stream>>>(Y1, Y2, (const int2*)pairs, E, s0);
  finalize_relu_f32bf16<<<(N * 32 + 255) / 256, 256, 0, stream>>>(s0, rowptr, xb, N * 32, 32);
  // Layer 1: IN=128, O=64, HS=8
  node_gemm<128, 64, 3><<<GG3, 256, 0, stream>>>(xb, N, NT, wp1, bias1, Y1, Y2);
  edge_attn_kernel<64, 8><<<EGRID, 512, 0, stream>>>(Y1, Y2, (const int2*)(pairs + E), E, s1);
  finalize_relu_bf16<<<(N * 16 + 255) / 256, 256, 0, stream>>>(s1, rowptr + RP, xb, N * 16, 16);
  // Layer 2: IN=64, O=128, HS=16 -> accumulate into d_out
  node_gemm<64, 128, 6><<<GG6, 256, 0, stream>>>(xb, N, NT, wp2, bias2, Y1, Y2);
  edge_attn_kernel<128, 16><<<EGRID, 512, 0, stream>>>(Y1, Y2, (const int2*)(pairs + 2 * (size_t)E),
                                                       E, (float*)d_out);
  finalize_add_relu<<<(N * 32 + 255) / 256, 256, 0, stream>>>((float*)d_out, s0, rowptr + 2 * RP,
                                                              N * 32, 32);
}

// Round 6
// 523.890 us; speedup vs baseline: 1.0138x; 1.0138x over previous
//
#include <hip/hip_runtime.h>
#include <hip/hip_fp16.h>

// EdgeConvEncoder R14 (on R10/R13-equivalent):
//  - Y1/Y2 switched bf16 -> IEEE fp16. edge_attn was VALU-bound with ~half the
//    VALU slots spent unpacking bf16 pairs to f32 (12 ops/dword across 6
//    arrays). fp16 enables native packed math (v_pk_add_f16/v_pk_mul_f16) on
//    the raw dwords: q1+q2, k1+k2, v1+v2, q*k with ZERO unpack; only exp input
//    and V product convert to f32 (op_sel hi is free). 19 -> 11 VALU/dword.
//  - node_gemm: mfma_f32_16x16x32_f16 (same fragment layout/rate as bf16).
//  - byte-neutral; precision improves (10-bit mantissa).

typedef _Float16 f16x8 __attribute__((ext_vector_type(8)));
typedef unsigned int u32x4 __attribute__((ext_vector_type(4)));
typedef float f32x4 __attribute__((ext_vector_type(4)));
typedef float f32x2 __attribute__((ext_vector_type(2)));

__device__ __forceinline__ unsigned short f2bf(float f) {
  unsigned int u = __float_as_uint(f);
  u += 0x7FFFu + ((u >> 16) & 1u);  // round-to-nearest-even
  return (unsigned short)(u >> 16);
}
__device__ __forceinline__ unsigned short f2h(float f) {
  __half h = __float2half(f);
  return *reinterpret_cast<unsigned short*>(&h);
}
__device__ __forceinline__ __half2 ash2(unsigned w) {
  return *reinterpret_cast<__half2*>(&w);
}

// ---------------- weight packing: 6 matrices (W1=top-bot x3, W2=bot x3) ----
__device__ __forceinline__ void pack_w_seg(const float* __restrict__ wq,
                                           const float* __restrict__ wk,
                                           const float* __restrict__ wv,
                                           unsigned short* __restrict__ dst,
                                           int IN, int O, float kscale, int id) {
  int kchunks = IN >> 5, nchunks = O >> 4;
  int total = 6 * nchunks * kchunks * 64;
  if (id >= total) return;
  int lane = id & 63;
  int frag = id >> 6;
  int kc = frag % kchunks;
  int nc = (frag / kchunks) % nchunks;
  int mat = frag / (kchunks * nchunks);
  const float* w = (mat % 3 == 0) ? wq : (mat % 3 == 1) ? wk : wv;
  float mul = (mat % 3 == 1) ? kscale : 1.0f;
  int n = nc * 16 + (lane & 15);
  int k0 = kc * 32 + (lane >> 4) * 8;
  unsigned short tmp[8];
#pragma unroll
  for (int j = 0; j < 8; ++j) {
    int row = k0 + j;
    float bot = w[(size_t)(IN + row) * O + n];
    float val = (mat < 3) ? (w[(size_t)row * O + n] - bot) : bot;
    tmp[j] = f2h(val * mul);
  }
  uint4 o;
  o.x = (unsigned)tmp[0] | ((unsigned)tmp[1] << 16);
  o.y = (unsigned)tmp[2] | ((unsigned)tmp[3] << 16);
  o.z = (unsigned)tmp[4] | ((unsigned)tmp[5] << 16);
  o.w = (unsigned)tmp[6] | ((unsigned)tmp[7] << 16);
  reinterpret_cast<uint4*>(dst)[id] = o;
}

__device__ __forceinline__ void pack_b_seg(const float* __restrict__ bq,
                                           const float* __restrict__ bk,
                                           const float* __restrict__ bv, float kscale, int O,
                                           float* __restrict__ out, int i) {
  int mat = i / O, c = i % O;
  float v = 0.f;
  if (mat == 0) v = bq[c];
  else if (mat == 1) v = bk[c] * kscale;
  else if (mat == 2) v = bv[c];
  out[i] = v;
}

// ---------------- fused preprocessing ----------------
// zeros (hist, s0+s1, d_out) + weight pack + bias pack + x f32->fp16
__global__ void preproc(
    uint4* __restrict__ z0, int n0, uint4* __restrict__ z1, int n1,
    uint4* __restrict__ z2, int n2,
    const float* __restrict__ x, unsigned short* __restrict__ xb, int n8,
    const float* __restrict__ wq0, const float* __restrict__ wk0, const float* __restrict__ wv0,
    const float* __restrict__ wq1, const float* __restrict__ wk1, const float* __restrict__ wv1,
    const float* __restrict__ wq2, const float* __restrict__ wk2, const float* __restrict__ wv2,
    unsigned short* __restrict__ wp0, unsigned short* __restrict__ wp1,
    unsigned short* __restrict__ wp2,
    const float* __restrict__ bq0, const float* __restrict__ bk0, const float* __restrict__ bv0,
    const float* __restrict__ bq1, const float* __restrict__ bk1, const float* __restrict__ bv1,
    const float* __restrict__ bq2, const float* __restrict__ bk2, const float* __restrict__ bv2,
    float* __restrict__ bias0, float* __restrict__ bias1, float* __restrict__ bias2,
    float sc16, float sc8) {
  const int tid = blockIdx.x * blockDim.x + threadIdx.x;
  const int stride = gridDim.x * blockDim.x;
  const uint4 Z = make_uint4(0u, 0u, 0u, 0u);
  for (int j = tid; j < n0; j += stride) z0[j] = Z;
  for (int j = tid; j < n1; j += stride) z1[j] = Z;
  for (int j = tid; j < n2; j += stride) z2[j] = Z;
  for (int j = tid; j < n8; j += stride) {
    float4 a = reinterpret_cast<const float4*>(x)[2 * j];
    float4 b = reinterpret_cast<const float4*>(x)[2 * j + 1];
    uint4 o;
    o.x = (unsigned)f2h(a.x) | ((unsigned)f2h(a.y) << 16);
    o.y = (unsigned)f2h(a.z) | ((unsigned)f2h(a.w) << 16);
    o.z = (unsigned)f2h(b.x) | ((unsigned)f2h(b.y) << 16);
    o.w = (unsigned)f2h(b.z) | ((unsigned)f2h(b.w) << 16);
    reinterpret_cast<uint4*>(xb)[j] = o;
  }
  if (tid < 12288) pack_w_seg(wq0, wk0, wv0, wp0, 128, 128, sc16, tid);
  else if (tid < 18432) pack_w_seg(wq1, wk1, wv1, wp1, 128, 64, sc8, tid - 12288);
  else if (tid < 24576) pack_w_seg(wq2, wk2, wv2, wp2, 64, 128, sc16, tid - 18432);
  else if (tid < 24576 + 1920) {
    int i = tid - 24576;
    if (i < 768) pack_b_seg(bq0, bk0, bv0, sc16, 128, bias0, i);
    else if (i < 1152) pack_b_seg(bq1, bk1, bv1, sc8, 64, bias1, i - 768);
    else pack_b_seg(bq2, bk2, bv2, sc16, 128, bias2, i - 1152);
  }
}

// ---------------- counting sort by dst ----------------
__global__ void hist3(const int* __restrict__ e0, const int* __restrict__ e1,
                      const int* __restrict__ e2, int E, int* __restrict__ hist,
                      int* __restrict__ rank, int NP) {
  int i = blockIdx.x * blockDim.x + threadIdx.x;
  if (i >= E) return;
  rank[0 * E + i] = atomicAdd(&hist[0 * NP + e0[E + i]], 1);
  rank[1 * E + i] = atomicAdd(&hist[1 * NP + e1[E + i]], 1);
  rank[2 * E + i] = atomicAdd(&hist[2 * NP + e2[E + i]], 1);
}

__device__ __forceinline__ int block_scan_excl256(int v, int* buf, int t, int* total) {
  buf[t] = v;
  __syncthreads();
#pragma unroll
  for (int off = 1; off < 256; off <<= 1) {
    int add = (t >= off) ? buf[t - off] : 0;
    __syncthreads();
    buf[t] += add;
    __syncthreads();
  }
  int incl = buf[t];
  *total = buf[255];
  __syncthreads();
  return incl - v;
}

__global__ void scan_pass1(const int* __restrict__ hist, int* __restrict__ excl,
                           int* __restrict__ bsum, int n, int NP) {
  __shared__ int buf[256];
  int y = blockIdx.y, t = threadIdx.x;
  int i = blockIdx.x * 256 + t;
  int v = (i < n) ? hist[y * NP + i] : 0;
  int total;
  int ex = block_scan_excl256(v, buf, t, &total);
  if (i < NP) excl[y * NP + i] = ex;
  if (t == 0) bsum[y * 256 + blockIdx.x] = total;
}

__global__ void scan_pass2(int* __restrict__ bsum, int nblk) {
  __shared__ int buf[256];
  int y = blockIdx.y, t = threadIdx.x;
  int v = (t < nblk) ? bsum[y * 256 + t] : 0;
  int total;
  int ex = block_scan_excl256(v, buf, t, &total);
  bsum[y * 256 + t] = ex;
}

__global__ void scan_pass3(const int* __restrict__ excl, const int* __restrict__ bsum,
                           int* __restrict__ rowptr, int n, int NP, int RP, int E) {
  int y = blockIdx.y;
  int i = blockIdx.x * 256 + threadIdx.x;
  if (i < n) rowptr[y * RP + i] = excl[y * NP + i] + bsum[y * 256 + blockIdx.x];
  if (i == 0) rowptr[y * RP + n] = E;
}

// scatter: pos = rowptr[d] + rank (no atomics); nontemporal 8B store
__global__ void scatter3(const int* __restrict__ e0, const int* __restrict__ e1,
                         const int* __restrict__ e2, int E, const int* __restrict__ rowptr,
                         const int* __restrict__ rank, long long* __restrict__ pairs,
                         int NP, int RP) {
  int y = blockIdx.y;
  const int* e = (y == 0) ? e0 : (y == 1) ? e1 : e2;
  int i = blockIdx.x * 256 + threadIdx.x;
  if (i >= E) return;
  int sN = e[i], d = e[E + i];
  int pos = rowptr[y * RP + d] + rank[(size_t)y * E + i];
  long long val = ((long long)(unsigned)d << 32) | (unsigned)sN;  // x=sN, y=d
  __builtin_nontemporal_store(val, &pairs[(size_t)y * E + pos]);
}

// ---------------- node-level GEMM (fp16 MFMA) ----------------
// 1-D padded grid, bijective XCD swizzle; logical lb -> (tile = lb/G, grp = lb%G)
template <int IN, int O, int G>
__global__ __launch_bounds__(256, 4) void node_gemm(
    const unsigned short* __restrict__ xb, int N, int NT,
    const unsigned short* __restrict__ wpack, const float* __restrict__ bias6,
    unsigned short* __restrict__ Y1, unsigned short* __restrict__ Y2) {
  constexpr int KC = IN / 32;
  constexpr int NCH = O / 16;
  constexpr int CHR = IN / 8;
  constexpr int CM = CHR - 1;
  __shared__ unsigned short tiles[64 * IN];

  const int chunk = gridDim.x >> 3;  // grid is a multiple of 8
  const int lb = (blockIdx.x & 7) * chunk + (blockIdx.x >> 3);
  if (lb >= NT * G) return;
  const int tile = lb / G;
  const int grp = lb % G;

  const int t = threadIdx.x, w = t >> 6, ln = t & 63;
  const int n0 = tile * 64;

  {
    constexpr int RPI = 64 / CHR;
    constexpr int NI = 16 / RPI;
    const int r_in = ln / CHR, c = ln % CHR;
#pragma unroll
    for (int i = 0; i < NI; ++i) {
      int row = w * 16 + i * RPI + r_in;
      int node = min(n0 + row, N - 1);
      int sc = c ^ (row & CM);
      const unsigned short* g = xb + (size_t)node * IN + sc * 8;
      unsigned short* l = &tiles[(size_t)(w * 16 + i * RPI) * IN];
      __builtin_amdgcn_global_load_lds(
          (const __attribute__((address_space(1))) unsigned int*)g,
          (__attribute__((address_space(3))) unsigned int*)l, 16, 0, 0);
    }
  }
  __syncthreads();

  const int col = ln & 15, quad = ln >> 4;
  const int g0 = grp * 8 + w * 2;

  f32x4 acc[2][4];
#pragma unroll
  for (int cc = 0; cc < 2; ++cc)
#pragma unroll
    for (int m = 0; m < 4; ++m) acc[cc][m] = (f32x4){0.f, 0.f, 0.f, 0.f};

#pragma unroll
  for (int kc = 0; kc < KC; ++kc) {
    f16x8 a[4];
#pragma unroll
    for (int m = 0; m < 4; ++m) {
      int row = m * 16 + col;
      int sc = (kc * 4 + quad) ^ (row & CM);
      a[m] = *reinterpret_cast<const f16x8*>(&tiles[(size_t)row * IN + sc * 8]);
    }
#pragma unroll
    for (int cc = 0; cc < 2; ++cc) {
      const f16x8 b = *reinterpret_cast<const f16x8*>(
          wpack + ((size_t)((g0 + cc) * KC + kc) * 64 + ln) * 8);
#pragma unroll
      for (int m = 0; m < 4; ++m)
        acc[cc][m] = __builtin_amdgcn_mfma_f32_16x16x32_f16(a[m], b, acc[cc][m], 0, 0, 0);
    }
  }

#pragma unroll
  for (int cc = 0; cc < 2; ++cc) {
    int gch = g0 + cc;
    int mat = gch / NCH, ncg = gch % NCH;
    unsigned short* Yp = (mat < 3) ? Y1 : Y2;
    int mo = (mat < 3) ? mat : mat - 3;
    float bv = bias6[gch * 16 + col];
    size_t coloff = (size_t)mo * O + ncg * 16 + col;
#pragma unroll
    for (int m = 0; m < 4; ++m)
#pragma unroll
      for (int r = 0; r < 4; ++r) {
        int node = n0 + m * 16 + quad * 4 + r;
        if (node < N) Yp[(size_t)node * (3 * O) + coloff] = f2h(acc[cc][m][r] + bv);
      }
  }
}

// ---------------- gather-based edge kernel (packed fp16 math) ----------------
// 512 threads, 64 edges, 8 threads/edge, thread = one head (HS channels).
// q1+q2 / k1+k2 / v1+v2 / q*k via v_pk_*_f16 directly on loaded dwords;
// f32 only for exp2, sum, and the PV product.
template <int O, int HS>
__global__ __launch_bounds__(512, 6) void edge_attn_kernel(
    const unsigned short* __restrict__ Y1, const unsigned short* __restrict__ Y2,
    const int2* __restrict__ pairs, const int E, float* __restrict__ s) {
  constexpr int NL = HS / 8;
  constexpr int PM = O / 4 - 1;
  __shared__ float ctx[64 * O];
  __shared__ int dstL[64];

  const int chunkB = gridDim.x >> 3;
  const int lb = (blockIdx.x & 7) * chunkB + (blockIdx.x >> 3);
  if (lb * 64 >= E) return;

  const int t = threadIdx.x;
  const int e = t >> 3, head = t & 7;
  const int eG = lb * 64 + e;
  const int eC = min(eG, E - 1);
  const bool valid = eG < E;
  const int2 p = pairs[eC];
  const int sN = p.x, dN = p.y;
  if ((t & 7) == 0) dstL[e] = dN;
  const float dd = fabsf((float)(dN - sN));
  const float ew = (dd > 8.f) ? 1.f : ((dd == 8.f) ? 0.f : -1.f);

  const unsigned short* b1 = Y1 + (size_t)dN * (3 * O) + head * HS;
  const unsigned short* b2 = Y2 + (size_t)sN * (3 * O) + head * HS;

  u32x4 q1[NL], q2[NL], k1[NL], k2[NL], v1[NL], v2[NL];
#pragma unroll
  for (int l = 0; l < NL; ++l) {
    q1[l] = *reinterpret_cast<const u32x4*>(b1 + l * 8);
    q2[l] = *reinterpret_cast<const u32x4*>(b2 + l * 8);
    k1[l] = *reinterpret_cast<const u32x4*>(b1 + O + l * 8);
    k2[l] = *reinterpret_cast<const u32x4*>(b2 + O + l * 8);
    v1[l] = *reinterpret_cast<const u32x4*>(b1 + 2 * O + l * 8);
    v2[l] = *reinterpret_cast<const u32x4*>(b2 + 2 * O + l * 8);
  }

  f32x2 ex2[NL * 4];
  f32x2 sum2 = (f32x2){0.f, 0.f};
#pragma unroll
  for (int l = 0; l < NL; ++l)
#pragma unroll
    for (int d = 0; d < 4; ++d) {
      __half2 qh = __hadd2(ash2(q1[l][d]), ash2(q2[l][d]));
      __half2 kh = __hadd2(ash2(k1[l][d]), ash2(k2[l][d]));
      __half2 qk = __hmul2(qh, kh);  // log2e*scale already folded into k
      f32x2 eo;
      eo.x = exp2f(__low2float(qk));
      eo.y = exp2f(__high2float(qk));
      ex2[l * 4 + d] = eo;
      sum2 += eo;
    }
  const float sum = sum2.x + sum2.y;
  const float rs = valid ? (ew / sum) : 0.f;
  const f32x2 rs2 = (f32x2){rs, rs};
#pragma unroll
  for (int l = 0; l < NL; ++l) {
#pragma unroll
    for (int g2 = 0; g2 < 2; ++g2) {
      __half2 va = __hadd2(ash2(v1[l][g2 * 2]), ash2(v2[l][g2 * 2]));
      __half2 vb = __hadd2(ash2(v1[l][g2 * 2 + 1]), ash2(v2[l][g2 * 2 + 1]));
      f32x2 vva = (f32x2){__low2float(va), __high2float(va)};
      f32x2 vvb = (f32x2){__low2float(vb), __high2float(vb)};
      f32x2 oa = ex2[l * 4 + g2 * 2] * rs2 * vva;
      f32x2 ob = ex2[l * 4 + g2 * 2 + 1] * rs2 * vvb;
      f32x4 o = (f32x4){oa.x, oa.y, ob.x, ob.y};
      int g = l * 2 + g2;
      int pch = (g * 8 + head + e) & PM;
      *reinterpret_cast<f32x4*>(&ctx[e * O + pch * 4]) = o;
    }
  }
  __syncthreads();

  {
    constexpr int GRP = 512 / O;
    constexpr int EPT = 64 / GRP;
    const int hs2 = t & 7;
    const int cs = (t >> 3) & (HS - 1);
    const int colA = hs2 * HS + cs;
    const int seg0 = (t / O) * EPT;
    const int inv = (cs >> 2) * 8 + hs2;
    const int js = cs & 3;
    float run = 0.f;
    int runstart = 0;           // i where current run began (0 => may predate segment)
    int dcur = dstL[seg0];
#pragma unroll
    for (int i = 0; i < EPT; ++i) {
      int ee = seg0 + i;
      int pch = (inv + ee) & PM;
      run += ctx[ee * O + pch * 4 + js];
      int dnext = (i < EPT - 1) ? dstL[ee + 1] : -1;
      if (dnext != dcur) {
        float* addr = &s[(size_t)dcur * O + colA];
        // run fully contained in this thread's segment -> exclusive -> plain store
        if (runstart > 0 && i < EPT - 1) *addr = run;
        else atomicAdd(addr, run);
        run = 0.f;
        runstart = i + 1;
        dcur = dnext;
      }
    }
  }
}

// ---------------- finalize ----------------
__global__ void finalize_relu_f32h(float* __restrict__ s, const int* __restrict__ rowptr,
                                   unsigned short* __restrict__ xbo, int total4, int Odiv4) {
  int i = blockIdx.x * blockDim.x + threadIdx.x;
  if (i >= total4) return;
  int node = i / Odiv4;
  float c = fmaxf((float)(rowptr[node + 1] - rowptr[node]), 1.0f);
  float4 v = reinterpret_cast<float4*>(s)[i];
  v.x = fmaxf(v.x / c, 0.f);
  v.y = fmaxf(v.y / c, 0.f);
  v.z = fmaxf(v.z / c, 0.f);
  v.w = fmaxf(v.w / c, 0.f);
  reinterpret_cast<float4*>(s)[i] = v;
  ushort4 o = make_ushort4(f2h(v.x), f2h(v.y), f2h(v.z), f2h(v.w));
  reinterpret_cast<ushort4*>(xbo)[i] = o;
}

__global__ void finalize_relu_h(const float* __restrict__ s, const int* __restrict__ rowptr,
                                unsigned short* __restrict__ xbo, int total4, int Odiv4) {
  int i = blockIdx.x * blockDim.x + threadIdx.x;
  if (i >= total4) return;
  int node = i / Odiv4;
  float c = fmaxf((float)(rowptr[node + 1] - rowptr[node]), 1.0f);
  float4 v = reinterpret_cast<const float4*>(s)[i];
  ushort4 o = make_ushort4(f2h(fmaxf(v.x / c, 0.f)), f2h(fmaxf(v.y / c, 0.f)),
                           f2h(fmaxf(v.z / c, 0.f)), f2h(fmaxf(v.w / c, 0.f)));
  reinterpret_cast<ushort4*>(xbo)[i] = o;
}

__global__ void finalize_add_relu(float* __restrict__ out, const float* __restrict__ x0,
                                  const int* __restrict__ rowptr, int total4, int Odiv4) {
  int i = blockIdx.x * blockDim.x + threadIdx.x;
  if (i >= total4) return;
  int node = i / Odiv4;
  float c = fmaxf((float)(rowptr[node + 1] - rowptr[node]), 1.0f);
  float4 v = reinterpret_cast<float4*>(out)[i];
  float4 r = reinterpret_cast<const float4*>(x0)[i];
  v.x = fmaxf(v.x / c + r.x, 0.f);
  v.y = fmaxf(v.y / c + r.y, 0.f);
  v.z = fmaxf(v.z / c + r.z, 0.f);
  v.w = fmaxf(v.w / c + r.w, 0.f);
  reinterpret_cast<float4*>(out)[i] = v;
}

extern "C" void kernel_launch(void* const* d_in, const int* in_sizes, int n_in,
                              void* d_out, int out_size, void* d_ws, size_t ws_size,
                              hipStream_t stream) {
  const float* x = (const float*)d_in[0];
  const int* e0 = (const int*)d_in[1];
  const int* e1 = (const int*)d_in[2];
  const int* e2 = (const int*)d_in[3];
  const float* wq0 = (const float*)d_in[5];
  const float* bq0 = (const float*)d_in[6];
  const float* wk0 = (const float*)d_in[7];
  const float* bk0 = (const float*)d_in[8];
  const float* wv0 = (const float*)d_in[9];
  const float* bv0 = (const float*)d_in[10];
  const float* wq1 = (const float*)d_in[11];
  const float* bq1 = (const float*)d_in[12];
  const float* wk1 = (const float*)d_in[13];
  const float* bk1 = (const float*)d_in[14];
  const float* wv1 = (const float*)d_in[15];
  const float* bv1 = (const float*)d_in[16];
  const float* wq2 = (const float*)d_in[17];
  const float* bq2 = (const float*)d_in[18];
  const float* wk2 = (const float*)d_in[19];
  const float* bk2 = (const float*)d_in[20];
  const float* wv2 = (const float*)d_in[21];
  const float* bv2 = (const float*)d_in[22];

  const int N = in_sizes[0] / 128;  // 50000
  const int E = in_sizes[1] / 2;    // 500000
  const int NBLK = (N + 255) / 256;
  const int NP = NBLK * 256;
  const int RP = NP + 256;
  const float LOG2E = 1.4426950408889634f;
  const float SC16 = 0.25f * LOG2E;                 // 1/sqrt(16) * log2e
  const float SC8 = 0.35355339059327373f * LOG2E;   // 1/sqrt(8)  * log2e

  // ---- workspace carve-up ----
  unsigned short* wp0 = (unsigned short*)d_ws;       // 98304 shorts
  unsigned short* wp1 = wp0 + 98304;                 // 49152
  unsigned short* wp2 = wp1 + 49152;                 // 49152
  float* bias0 = (float*)(wp2 + 49152);              // 768
  float* bias1 = bias0 + 768;                        // 384
  float* bias2 = bias1 + 384;                        // 768
  unsigned short* xb = (unsigned short*)(bias2 + 768);  // N*128
  unsigned short* Y1 = xb + (size_t)N * 128;         // N*384
  unsigned short* Y2 = Y1 + (size_t)N * 384;         // N*384
  float* s0 = (float*)(Y2 + (size_t)N * 384);        // N*128
  float* s1 = s0 + (size_t)N * 128;                  // N*64
  int* hist = (int*)(s1 + (size_t)N * 64);           // 3*NP
  int* excl = hist + 3 * (size_t)NP;                 // 3*NP
  int* bsum = excl + 3 * (size_t)NP;                 // 768
  int* rowptr = bsum + 768;                          // 3*RP
  int* rank = rowptr + 3 * (size_t)RP;               // 3*E
  long long* pairs = (long long*)(rank + 3 * (size_t)E + 2);  // 3*E (8B aligned)

  // fused preprocessing: zeros + weight/bias pack + x->fp16
  preproc<<<2048, 256, 0, stream>>>(
      (uint4*)hist, 3 * NP / 4, (uint4*)s0, N * 48, (uint4*)d_out, out_size / 4,
      x, xb, N * 16,
      wq0, wk0, wv0, wq1, wk1, wv1, wq2, wk2, wv2, wp0, wp1, wp2,
      bq0, bk0, bv0, bq1, bk1, bv1, bq2, bk2, bv2, bias0, bias1, bias2,
      SC16, SC8);

  const int EB256 = (E + 255) / 256;
  hist3<<<EB256, 256, 0, stream>>>(e0, e1, e2, E, hist, rank, NP);
  scan_pass1<<<dim3(NBLK, 3), 256, 0, stream>>>(hist, excl, bsum, N, NP);
  scan_pass2<<<dim3(1, 3), 256, 0, stream>>>(bsum, NBLK);
  scan_pass3<<<dim3(NBLK, 3), 256, 0, stream>>>(excl, bsum, rowptr, N, NP, RP, E);
  scatter3<<<dim3(EB256, 3), 256, 0, stream>>>(e0, e1, e2, E, rowptr, rank, pairs, NP, RP);

  const int NT = (N + 63) / 64;
  const int EBK = (E + 63) / 64;
  const int EGRID = 8 * ((EBK + 7) / 8);  // bijective XCD swizzle grid
  const int GG6 = 8 * ((NT * 6 + 7) / 8);
  const int GG3 = 8 * ((NT * 3 + 7) / 8);

  // Layer 0: IN=128, O=128, HS=16
  node_gemm<128, 128, 6><<<GG6, 256, 0, stream>>>(xb, N, NT, wp0, bias0, Y1, Y2);
  edge_attn_kernel<128, 16><<<EGRID, 512, 0, stream>>>(Y1, Y2, (const int2*)pairs, E, s0);
  finalize_relu_f32h<<<(N * 32 + 255) / 256, 256, 0, stream>>>(s0, rowptr, xb, N * 32, 32);
  // Layer 1: IN=128, O=64, HS=8
  node_gemm<128, 64, 3><<<GG3, 256, 0, stream>>>(xb, N, NT, wp1, bias1, Y1, Y2);
  edge_attn_kernel<64, 8><<<EGRID, 512, 0, stream>>>(Y1, Y2, (const int2*)(pairs + E), E, s1);
  finalize_relu_h<<<(N * 16 + 255) / 256, 256, 0, stream>>>(s1, rowptr + RP, xb, N * 16, 16);
  // Layer 2: IN=64, O=128, HS=16 -> accumulate into d_out
  node_gemm<64, 128, 6><<<GG6, 256, 0, stream>>>(xb, N, NT, wp2, bias2, Y1, Y2);
  edge_attn_kernel<128, 16><<<EGRID, 512, 0, stream>>>(Y1, Y2, (const int2*)(pairs + 2 * (size_t)E),
                                                       E, (float*)d_out);
  finalize_add_relu<<<(N * 32 + 255) / 256, 256, 0, stream>>>((float*)d_out, s0, rowptr + 2 * RP,
                                                              N * 32, 32);
}

// Round 7
// 520.464 us; speedup vs baseline: 1.0204x; 1.0066x over previous
//
#include <hip/hip_runtime.h>
#include <hip/hip_fp16.h>

// EdgeConvEncoder R15 (on R14):
//  - hist3 fused into preproc (hist zeroed by hipMemsetAsync before): the
//    1.5M rank-atomics (latency-bound, VALU 0.4%) overlap preproc's ~100MB
//    streaming. Standalone hist3 was 70us, fully serialized.
//  - scatter3 fused into gemm0 as extra blocks (both depend only on
//    preproc+scans; nothing in-dispatch reads pairs): random 8B scatter
//    overlaps MFMA/staging. Gemm swizzle keyed off gemmBlks (not gridDim),
//    XCD mapping unchanged.
//  - edge_attn unchanged (R14 fp16): 4 attempts proved it memory-service
//    bound at ~69.5us; VALU/sched changes don't move it.

typedef _Float16 f16x8 __attribute__((ext_vector_type(8)));
typedef unsigned int u32x4 __attribute__((ext_vector_type(4)));
typedef float f32x4 __attribute__((ext_vector_type(4)));
typedef float f32x2 __attribute__((ext_vector_type(2)));

__device__ __forceinline__ unsigned short f2h(float f) {
  __half h = __float2half(f);
  return *reinterpret_cast<unsigned short*>(&h);
}
__device__ __forceinline__ __half2 ash2(unsigned w) {
  return *reinterpret_cast<__half2*>(&w);
}

// ---------------- weight packing: 6 matrices (W1=top-bot x3, W2=bot x3) ----
__device__ __forceinline__ void pack_w_seg(const float* __restrict__ wq,
                                           const float* __restrict__ wk,
                                           const float* __restrict__ wv,
                                           unsigned short* __restrict__ dst,
                                           int IN, int O, float kscale, int id) {
  int kchunks = IN >> 5, nchunks = O >> 4;
  int total = 6 * nchunks * kchunks * 64;
  if (id >= total) return;
  int lane = id & 63;
  int frag = id >> 6;
  int kc = frag % kchunks;
  int nc = (frag / kchunks) % nchunks;
  int mat = frag / (kchunks * nchunks);
  const float* w = (mat % 3 == 0) ? wq : (mat % 3 == 1) ? wk : wv;
  float mul = (mat % 3 == 1) ? kscale : 1.0f;
  int n = nc * 16 + (lane & 15);
  int k0 = kc * 32 + (lane >> 4) * 8;
  unsigned short tmp[8];
#pragma unroll
  for (int j = 0; j < 8; ++j) {
    int row = k0 + j;
    float bot = w[(size_t)(IN + row) * O + n];
    float val = (mat < 3) ? (w[(size_t)row * O + n] - bot) : bot;
    tmp[j] = f2h(val * mul);
  }
  uint4 o;
  o.x = (unsigned)tmp[0] | ((unsigned)tmp[1] << 16);
  o.y = (unsigned)tmp[2] | ((unsigned)tmp[3] << 16);
  o.z = (unsigned)tmp[4] | ((unsigned)tmp[5] << 16);
  o.w = (unsigned)tmp[6] | ((unsigned)tmp[7] << 16);
  reinterpret_cast<uint4*>(dst)[id] = o;
}

__device__ __forceinline__ void pack_b_seg(const float* __restrict__ bq,
                                           const float* __restrict__ bk,
                                           const float* __restrict__ bv, float kscale, int O,
                                           float* __restrict__ out, int i) {
  int mat = i / O, c = i % O;
  float v = 0.f;
  if (mat == 0) v = bq[c];
  else if (mat == 1) v = bk[c] * kscale;
  else if (mat == 2) v = bv[c];
  out[i] = v;
}

// ---------------- fused preprocessing + edge histogram ----------------
// hist atomics (rank capture) + zeros (s0+s1, d_out) + weight/bias pack +
// x f32->fp16. hist must be zeroed BEFORE this kernel (hipMemsetAsync).
__global__ void preproc(
    const int* __restrict__ e0, const int* __restrict__ e1, const int* __restrict__ e2,
    int E, int* __restrict__ hist, int* __restrict__ rank, int NP,
    uint4* __restrict__ za, int na, uint4* __restrict__ zb, int nb,
    const float* __restrict__ x, unsigned short* __restrict__ xb, int n8,
    const float* __restrict__ wq0, const float* __restrict__ wk0, const float* __restrict__ wv0,
    const float* __restrict__ wq1, const float* __restrict__ wk1, const float* __restrict__ wv1,
    const float* __restrict__ wq2, const float* __restrict__ wk2, const float* __restrict__ wv2,
    unsigned short* __restrict__ wp0, unsigned short* __restrict__ wp1,
    unsigned short* __restrict__ wp2,
    const float* __restrict__ bq0, const float* __restrict__ bk0, const float* __restrict__ bv0,
    const float* __restrict__ bq1, const float* __restrict__ bk1, const float* __restrict__ bv1,
    const float* __restrict__ bq2, const float* __restrict__ bk2, const float* __restrict__ bv2,
    float* __restrict__ bias0, float* __restrict__ bias1, float* __restrict__ bias2,
    float sc16, float sc8) {
  const int tid = blockIdx.x * blockDim.x + threadIdx.x;
  const int stride = gridDim.x * blockDim.x;

  // edge histogram + rank (atomic returns); latency hides under streaming below
  for (int i = tid; i < E; i += stride) {
    rank[i] = atomicAdd(&hist[e0[E + i]], 1);
    rank[(size_t)E + i] = atomicAdd(&hist[NP + e1[E + i]], 1);
    rank[2 * (size_t)E + i] = atomicAdd(&hist[2 * NP + e2[E + i]], 1);
  }

  const uint4 Z = make_uint4(0u, 0u, 0u, 0u);
  for (int j = tid; j < na; j += stride) za[j] = Z;
  for (int j = tid; j < nb; j += stride) zb[j] = Z;
  for (int j = tid; j < n8; j += stride) {
    float4 a = reinterpret_cast<const float4*>(x)[2 * j];
    float4 b = reinterpret_cast<const float4*>(x)[2 * j + 1];
    uint4 o;
    o.x = (unsigned)f2h(a.x) | ((unsigned)f2h(a.y) << 16);
    o.y = (unsigned)f2h(a.z) | ((unsigned)f2h(a.w) << 16);
    o.z = (unsigned)f2h(b.x) | ((unsigned)f2h(b.y) << 16);
    o.w = (unsigned)f2h(b.z) | ((unsigned)f2h(b.w) << 16);
    reinterpret_cast<uint4*>(xb)[j] = o;
  }
  if (tid < 12288) pack_w_seg(wq0, wk0, wv0, wp0, 128, 128, sc16, tid);
  else if (tid < 18432) pack_w_seg(wq1, wk1, wv1, wp1, 128, 64, sc8, tid - 12288);
  else if (tid < 24576) pack_w_seg(wq2, wk2, wv2, wp2, 64, 128, sc16, tid - 18432);
  else if (tid < 24576 + 1920) {
    int i = tid - 24576;
    if (i < 768) pack_b_seg(bq0, bk0, bv0, sc16, 128, bias0, i);
    else if (i < 1152) pack_b_seg(bq1, bk1, bv1, sc8, 64, bias1, i - 768);
    else pack_b_seg(bq2, bk2, bv2, sc16, 128, bias2, i - 1152);
  }
}

// ---------------- scans ----------------
__device__ __forceinline__ int block_scan_excl256(int v, int* buf, int t, int* total) {
  buf[t] = v;
  __syncthreads();
#pragma unroll
  for (int off = 1; off < 256; off <<= 1) {
    int add = (t >= off) ? buf[t - off] : 0;
    __syncthreads();
    buf[t] += add;
    __syncthreads();
  }
  int incl = buf[t];
  *total = buf[255];
  __syncthreads();
  return incl - v;
}

__global__ void scan_pass1(const int* __restrict__ hist, int* __restrict__ excl,
                           int* __restrict__ bsum, int n, int NP) {
  __shared__ int buf[256];
  int y = blockIdx.y, t = threadIdx.x;
  int i = blockIdx.x * 256 + t;
  int v = (i < n) ? hist[y * NP + i] : 0;
  int total;
  int ex = block_scan_excl256(v, buf, t, &total);
  if (i < NP) excl[y * NP + i] = ex;
  if (t == 0) bsum[y * 256 + blockIdx.x] = total;
}

__global__ void scan_pass2(int* __restrict__ bsum, int nblk) {
  __shared__ int buf[256];
  int y = blockIdx.y, t = threadIdx.x;
  int v = (t < nblk) ? bsum[y * 256 + t] : 0;
  int total;
  int ex = block_scan_excl256(v, buf, t, &total);
  bsum[y * 256 + t] = ex;
}

__global__ void scan_pass3(const int* __restrict__ excl, const int* __restrict__ bsum,
                           int* __restrict__ rowptr, int n, int NP, int RP, int E) {
  int y = blockIdx.y;
  int i = blockIdx.x * 256 + threadIdx.x;
  if (i < n) rowptr[y * RP + i] = excl[y * NP + i] + bsum[y * 256 + blockIdx.x];
  if (i == 0) rowptr[y * RP + n] = E;
}

// ---------------- node-level GEMM (fp16 MFMA), optional fused scatter ------
// gemm blocks: 1-D padded grid + bijective XCD swizzle keyed off gemmBlks.
// FS blocks (blockIdx >= gemmBlks): counting-sort scatter for all 3 layers
// (pos = rowptr[d] + rank, nontemporal 8B store) — overlaps gemm compute.
template <int IN, int O, int G, bool FS>
__global__ __launch_bounds__(256, 4) void node_gemm(
    const unsigned short* __restrict__ xb, int N, int NT,
    const unsigned short* __restrict__ wpack, const float* __restrict__ bias6,
    unsigned short* __restrict__ Y1, unsigned short* __restrict__ Y2,
    int gemmBlks,
    const int* __restrict__ e0, const int* __restrict__ e1, const int* __restrict__ e2,
    int E, const int* __restrict__ rowptr, const int* __restrict__ rank,
    long long* __restrict__ pairs, int RP) {
  constexpr int KC = IN / 32;
  constexpr int NCH = O / 16;
  constexpr int CHR = IN / 8;
  constexpr int CM = CHR - 1;
  __shared__ unsigned short tiles[64 * IN];

  if (FS) {
    if (blockIdx.x >= (unsigned)gemmBlks) {
      const int sidx = blockIdx.x - gemmBlks;
      const int EB = (E + 255) >> 8;
      const int y = sidx / EB;
      const int i = (sidx - y * EB) * 256 + threadIdx.x;
      if (i < E) {
        const int* e = (y == 0) ? e0 : (y == 1) ? e1 : e2;
        int sN = e[i], d = e[E + i];
        int pos = rowptr[y * RP + d] + rank[(size_t)y * E + i];
        long long val = ((long long)(unsigned)d << 32) | (unsigned)sN;  // x=sN, y=d
        __builtin_nontemporal_store(val, &pairs[(size_t)y * E + pos]);
      }
      return;
    }
  }

  const int chunk = gemmBlks >> 3;  // gemmBlks is a multiple of 8
  const int lb = (blockIdx.x & 7) * chunk + (blockIdx.x >> 3);
  if (lb >= NT * G) return;
  const int tile = lb / G;
  const int grp = lb % G;

  const int t = threadIdx.x, w = t >> 6, ln = t & 63;
  const int n0 = tile * 64;

  {
    constexpr int RPI = 64 / CHR;
    constexpr int NI = 16 / RPI;
    const int r_in = ln / CHR, c = ln % CHR;
#pragma unroll
    for (int i = 0; i < NI; ++i) {
      int row = w * 16 + i * RPI + r_in;
      int node = min(n0 + row, N - 1);
      int sc = c ^ (row & CM);
      const unsigned short* g = xb + (size_t)node * IN + sc * 8;
      unsigned short* l = &tiles[(size_t)(w * 16 + i * RPI) * IN];
      __builtin_amdgcn_global_load_lds(
          (const __attribute__((address_space(1))) unsigned int*)g,
          (__attribute__((address_space(3))) unsigned int*)l, 16, 0, 0);
    }
  }
  __syncthreads();

  const int col = ln & 15, quad = ln >> 4;
  const int g0 = grp * 8 + w * 2;

  f32x4 acc[2][4];
#pragma unroll
  for (int cc = 0; cc < 2; ++cc)
#pragma unroll
    for (int m = 0; m < 4; ++m) acc[cc][m] = (f32x4){0.f, 0.f, 0.f, 0.f};

#pragma unroll
  for (int kc = 0; kc < KC; ++kc) {
    f16x8 a[4];
#pragma unroll
    for (int m = 0; m < 4; ++m) {
      int row = m * 16 + col;
      int sc = (kc * 4 + quad) ^ (row & CM);
      a[m] = *reinterpret_cast<const f16x8*>(&tiles[(size_t)row * IN + sc * 8]);
    }
#pragma unroll
    for (int cc = 0; cc < 2; ++cc) {
      const f16x8 b = *reinterpret_cast<const f16x8*>(
          wpack + ((size_t)((g0 + cc) * KC + kc) * 64 + ln) * 8);
#pragma unroll
      for (int m = 0; m < 4; ++m)
        acc[cc][m] = __builtin_amdgcn_mfma_f32_16x16x32_f16(a[m], b, acc[cc][m], 0, 0, 0);
    }
  }

#pragma unroll
  for (int cc = 0; cc < 2; ++cc) {
    int gch = g0 + cc;
    int mat = gch / NCH, ncg = gch % NCH;
    unsigned short* Yp = (mat < 3) ? Y1 : Y2;
    int mo = (mat < 3) ? mat : mat - 3;
    float bv = bias6[gch * 16 + col];
    size_t coloff = (size_t)mo * O + ncg * 16 + col;
#pragma unroll
    for (int m = 0; m < 4; ++m)
#pragma unroll
      for (int r = 0; r < 4; ++r) {
        int node = n0 + m * 16 + quad * 4 + r;
        if (node < N) Yp[(size_t)node * (3 * O) + coloff] = f2h(acc[cc][m][r] + bv);
      }
  }
}

// ---------------- gather-based edge kernel (packed fp16 math) ----------------
// 512 threads, 64 edges, 8 threads/edge, thread = one head (HS channels).
template <int O, int HS>
__global__ __launch_bounds__(512, 6) void edge_attn_kernel(
    const unsigned short* __restrict__ Y1, const unsigned short* __restrict__ Y2,
    const int2* __restrict__ pairs, const int E, float* __restrict__ s) {
  constexpr int NL = HS / 8;
  constexpr int PM = O / 4 - 1;
  __shared__ float ctx[64 * O];
  __shared__ int dstL[64];

  const int chunkB = gridDim.x >> 3;
  const int lb = (blockIdx.x & 7) * chunkB + (blockIdx.x >> 3);
  if (lb * 64 >= E) return;

  const int t = threadIdx.x;
  const int e = t >> 3, head = t & 7;
  const int eG = lb * 64 + e;
  const int eC = min(eG, E - 1);
  const bool valid = eG < E;
  const int2 p = pairs[eC];
  const int sN = p.x, dN = p.y;
  if ((t & 7) == 0) dstL[e] = dN;
  const float dd = fabsf((float)(dN - sN));
  const float ew = (dd > 8.f) ? 1.f : ((dd == 8.f) ? 0.f : -1.f);

  const unsigned short* b1 = Y1 + (size_t)dN * (3 * O) + head * HS;
  const unsigned short* b2 = Y2 + (size_t)sN * (3 * O) + head * HS;

  u32x4 q1[NL], q2[NL], k1[NL], k2[NL], v1[NL], v2[NL];
#pragma unroll
  for (int l = 0; l < NL; ++l) {
    q1[l] = *reinterpret_cast<const u32x4*>(b1 + l * 8);
    q2[l] = *reinterpret_cast<const u32x4*>(b2 + l * 8);
    k1[l] = *reinterpret_cast<const u32x4*>(b1 + O + l * 8);
    k2[l] = *reinterpret_cast<const u32x4*>(b2 + O + l * 8);
    v1[l] = *reinterpret_cast<const u32x4*>(b1 + 2 * O + l * 8);
    v2[l] = *reinterpret_cast<const u32x4*>(b2 + 2 * O + l * 8);
  }

  f32x2 ex2[NL * 4];
  f32x2 sum2 = (f32x2){0.f, 0.f};
#pragma unroll
  for (int l = 0; l < NL; ++l)
#pragma unroll
    for (int d = 0; d < 4; ++d) {
      __half2 qh = __hadd2(ash2(q1[l][d]), ash2(q2[l][d]));
      __half2 kh = __hadd2(ash2(k1[l][d]), ash2(k2[l][d]));
      __half2 qk = __hmul2(qh, kh);  // log2e*scale already folded into k
      f32x2 eo;
      eo.x = exp2f(__low2float(qk));
      eo.y = exp2f(__high2float(qk));
      ex2[l * 4 + d] = eo;
      sum2 += eo;
    }
  const float sum = sum2.x + sum2.y;
  const float rs = valid ? (ew / sum) : 0.f;
  const f32x2 rs2 = (f32x2){rs, rs};
#pragma unroll
  for (int l = 0; l < NL; ++l) {
#pragma unroll
    for (int g2 = 0; g2 < 2; ++g2) {
      __half2 va = __hadd2(ash2(v1[l][g2 * 2]), ash2(v2[l][g2 * 2]));
      __half2 vb = __hadd2(ash2(v1[l][g2 * 2 + 1]), ash2(v2[l][g2 * 2 + 1]));
      f32x2 vva = (f32x2){__low2float(va), __high2float(va)};
      f32x2 vvb = (f32x2){__low2float(vb), __high2float(vb)};
      f32x2 oa = ex2[l * 4 + g2 * 2] * rs2 * vva;
      f32x2 ob = ex2[l * 4 + g2 * 2 + 1] * rs2 * vvb;
      f32x4 o = (f32x4){oa.x, oa.y, ob.x, ob.y};
      int g = l * 2 + g2;
      int pch = (g * 8 + head + e) & PM;
      *reinterpret_cast<f32x4*>(&ctx[e * O + pch * 4]) = o;
    }
  }
  __syncthreads();

  {
    constexpr int GRP = 512 / O;
    constexpr int EPT = 64 / GRP;
    const int hs2 = t & 7;
    const int cs = (t >> 3) & (HS - 1);
    const int colA = hs2 * HS + cs;
    const int seg0 = (t / O) * EPT;
    const int inv = (cs >> 2) * 8 + hs2;
    const int js = cs & 3;
    float run = 0.f;
    int runstart = 0;           // i where current run began (0 => may predate segment)
    int dcur = dstL[seg0];
#pragma unroll
    for (int i = 0; i < EPT; ++i) {
      int ee = seg0 + i;
      int pch = (inv + ee) & PM;
      run += ctx[ee * O + pch * 4 + js];
      int dnext = (i < EPT - 1) ? dstL[ee + 1] : -1;
      if (dnext != dcur) {
        float* addr = &s[(size_t)dcur * O + colA];
        // run fully contained in this thread's segment -> exclusive -> plain store
        if (runstart > 0 && i < EPT - 1) *addr = run;
        else atomicAdd(addr, run);
        run = 0.f;
        runstart = i + 1;
        dcur = dnext;
      }
    }
  }
}

// ---------------- finalize ----------------
__global__ void finalize_relu_f32h(float* __restrict__ s, const int* __restrict__ rowptr,
                                   unsigned short* __restrict__ xbo, int total4, int Odiv4) {
  int i = blockIdx.x * blockDim.x + threadIdx.x;
  if (i >= total4) return;
  int node = i / Odiv4;
  float c = fmaxf((float)(rowptr[node + 1] - rowptr[node]), 1.0f);
  float4 v = reinterpret_cast<float4*>(s)[i];
  v.x = fmaxf(v.x / c, 0.f);
  v.y = fmaxf(v.y / c, 0.f);
  v.z = fmaxf(v.z / c, 0.f);
  v.w = fmaxf(v.w / c, 0.f);
  reinterpret_cast<float4*>(s)[i] = v;
  ushort4 o = make_ushort4(f2h(v.x), f2h(v.y), f2h(v.z), f2h(v.w));
  reinterpret_cast<ushort4*>(xbo)[i] = o;
}

__global__ void finalize_relu_h(const float* __restrict__ s, const int* __restrict__ rowptr,
                                unsigned short* __restrict__ xbo, int total4, int Odiv4) {
  int i = blockIdx.x * blockDim.x + threadIdx.x;
  if (i >= total4) return;
  int node = i / Odiv4;
  float c = fmaxf((float)(rowptr[node + 1] - rowptr[node]), 1.0f);
  float4 v = reinterpret_cast<const float4*>(s)[i];
  ushort4 o = make_ushort4(f2h(fmaxf(v.x / c, 0.f)), f2h(fmaxf(v.y / c, 0.f)),
                           f2h(fmaxf(v.z / c, 0.f)), f2h(fmaxf(v.w / c, 0.f)));
  reinterpret_cast<ushort4*>(xbo)[i] = o;
}

__global__ void finalize_add_relu(float* __restrict__ out, const float* __restrict__ x0,
                                  const int* __restrict__ rowptr, int total4, int Odiv4) {
  int i = blockIdx.x * blockDim.x + threadIdx.x;
  if (i >= total4) return;
  int node = i / Odiv4;
  float c = fmaxf((float)(rowptr[node + 1] - rowptr[node]), 1.0f);
  float4 v = reinterpret_cast<float4*>(out)[i];
  float4 r = reinterpret_cast<const float4*>(x0)[i];
  v.x = fmaxf(v.x / c + r.x, 0.f);
  v.y = fmaxf(v.y / c + r.y, 0.f);
  v.z = fmaxf(v.z / c + r.z, 0.f);
  v.w = fmaxf(v.w / c + r.w, 0.f);
  reinterpret_cast<float4*>(out)[i] = v;
}

extern "C" void kernel_launch(void* const* d_in, const int* in_sizes, int n_in,
                              void* d_out, int out_size, void* d_ws, size_t ws_size,
                              hipStream_t stream) {
  const float* x = (const float*)d_in[0];
  const int* e0 = (const int*)d_in[1];
  const int* e1 = (const int*)d_in[2];
  const int* e2 = (const int*)d_in[3];
  const float* wq0 = (const float*)d_in[5];
  const float* bq0 = (const float*)d_in[6];
  const float* wk0 = (const float*)d_in[7];
  const float* bk0 = (const float*)d_in[8];
  const float* wv0 = (const float*)d_in[9];
  const float* bv0 = (const float*)d_in[10];
  const float* wq1 = (const float*)d_in[11];
  const float* bq1 = (const float*)d_in[12];
  const float* wk1 = (const float*)d_in[13];
  const float* bk1 = (const float*)d_in[14];
  const float* wv1 = (const float*)d_in[15];
  const float* bv1 = (const float*)d_in[16];
  const float* wq2 = (const float*)d_in[17];
  const float* bq2 = (const float*)d_in[18];
  const float* wk2 = (const float*)d_in[19];
  const float* bk2 = (const float*)d_in[20];
  const float* wv2 = (const float*)d_in[21];
  const float* bv2 = (const float*)d_in[22];

  const int N = in_sizes[0] / 128;  // 50000
  const int E = in_sizes[1] / 2;    // 500000
  const int NBLK = (N + 255) / 256;
  const int NP = NBLK * 256;
  const int RP = NP + 256;
  const float LOG2E = 1.4426950408889634f;
  const float SC16 = 0.25f * LOG2E;                 // 1/sqrt(16) * log2e
  const float SC8 = 0.35355339059327373f * LOG2E;   // 1/sqrt(8)  * log2e

  // ---- workspace carve-up ----
  unsigned short* wp0 = (unsigned short*)d_ws;       // 98304 shorts
  unsigned short* wp1 = wp0 + 98304;                 // 49152
  unsigned short* wp2 = wp1 + 49152;                 // 49152
  float* bias0 = (float*)(wp2 + 49152);              // 768
  float* bias1 = bias0 + 768;                        // 384
  float* bias2 = bias1 + 384;                        // 768
  unsigned short* xb = (unsigned short*)(bias2 + 768);  // N*128
  unsigned short* Y1 = xb + (size_t)N * 128;         // N*384
  unsigned short* Y2 = Y1 + (size_t)N * 384;         // N*384
  float* s0 = (float*)(Y2 + (size_t)N * 384);        // N*128
  float* s1 = s0 + (size_t)N * 128;                  // N*64
  int* hist = (int*)(s1 + (size_t)N * 64);           // 3*NP
  int* excl = hist + 3 * (size_t)NP;                 // 3*NP
  int* bsum = excl + 3 * (size_t)NP;                 // 768
  int* rowptr = bsum + 768;                          // 3*RP
  int* rank = rowptr + 3 * (size_t)RP;               // 3*E
  long long* pairs = (long long*)(rank + 3 * (size_t)E + 2);  // 3*E (8B aligned)

  hipMemsetAsync(hist, 0, 3 * (size_t)NP * sizeof(int), stream);

  // fused preprocessing: hist atomics + zeros + weight/bias pack + x->fp16
  preproc<<<2048, 256, 0, stream>>>(
      e0, e1, e2, E, hist, rank, NP,
      (uint4*)s0, N * 48, (uint4*)d_out, out_size / 4,
      x, xb, N * 16,
      wq0, wk0, wv0, wq1, wk1, wv1, wq2, wk2, wv2, wp0, wp1, wp2,
      bq0, bk0, bv0, bq1, bk1, bv1, bq2, bk2, bv2, bias0, bias1, bias2,
      SC16, SC8);

  scan_pass1<<<dim3(NBLK, 3), 256, 0, stream>>>(hist, excl, bsum, N, NP);
  scan_pass2<<<dim3(1, 3), 256, 0, stream>>>(bsum, NBLK);
  scan_pass3<<<dim3(NBLK, 3), 256, 0, stream>>>(excl, bsum, rowptr, N, NP, RP, E);

  const int NT = (N + 63) / 64;
  const int EBK = (E + 63) / 64;
  const int EGRID = 8 * ((EBK + 7) / 8);  // bijective XCD swizzle grid
  const int GG6 = 8 * ((NT * 6 + 7) / 8);
  const int GG3 = 8 * ((NT * 3 + 7) / 8);
  const int EB256 = (E + 255) / 256;

  // Layer 0: IN=128, O=128, HS=16 — gemm + fused scatter (all 3 layers)
  node_gemm<128, 128, 6, true><<<GG6 + 3 * EB256, 256, 0, stream>>>(
      xb, N, NT, wp0, bias0, Y1, Y2, GG6, e0, e1, e2, E, rowptr, rank, pairs, RP);
  edge_attn_kernel<128, 16><<<EGRID, 512, 0, stream>>>(Y1, Y2, (const int2*)pairs, E, s0);
  finalize_relu_f32h<<<(N * 32 + 255) / 256, 256, 0, stream>>>(s0, rowptr, xb, N * 32, 32);
  // Layer 1: IN=128, O=64, HS=8
  node_gemm<128, 64, 3, false><<<GG3, 256, 0, stream>>>(
      xb, N, NT, wp1, bias1, Y1, Y2, GG3, nullptr, nullptr, nullptr, 0, nullptr, nullptr,
      nullptr, 0);
  edge_attn_kernel<64, 8><<<EGRID, 512, 0, stream>>>(Y1, Y2, (const int2*)(pairs + E), E, s1);
  finalize_relu_h<<<(N * 16 + 255) / 256, 256, 0, stream>>>(s1, rowptr + RP, xb, N * 16, 16);
  // Layer 2: IN=64, O=128, HS=16 -> accumulate into d_out
  node_gemm<64, 128, 6, false><<<GG6, 256, 0, stream>>>(
      xb, N, NT, wp2, bias2, Y1, Y2, GG6, nullptr, nullptr, nullptr, 0, nullptr, nullptr,
      nullptr, 0);
  edge_attn_kernel<128, 16><<<EGRID, 512, 0, stream>>>(Y1, Y2, (const int2*)(pairs + 2 * (size_t)E),
                                                       E, (float*)d_out);
  finalize_add_relu<<<(N * 32 + 255) / 256, 256, 0, stream>>>((float*)d_out, s0, rowptr + 2 * RP,
                                                              N * 32, 32);
}

// Round 8
// 517.847 us; speedup vs baseline: 1.0256x; 1.0051x over previous
//
#include <hip/hip_runtime.h>
#include <hip/hip_fp16.h>

// EdgeConvEncoder R16 (on R15):
//  - REVERT scatter-gemm fusion (R15 measured: fused dispatch 90us vs
//    28+28 separate — gemm 2B Y-stores + scatter random 8B NT stores thrash
//    TCC write-allocate concurrently; scatter blocks serialized as tail).
//    scatter3 back to its own dispatch; node_gemm pure again.
//  - KEEP hist fusion in preproc (saved ~38us: standalone hist3 was 70us,
//    atomic service now hidden under preproc streaming).
//  - edge_attn unchanged (fp16 packed): at gather-service ceiling ~69.5us
//    (4 schedule variants identical).

typedef _Float16 f16x8 __attribute__((ext_vector_type(8)));
typedef unsigned int u32x4 __attribute__((ext_vector_type(4)));
typedef float f32x4 __attribute__((ext_vector_type(4)));
typedef float f32x2 __attribute__((ext_vector_type(2)));

__device__ __forceinline__ unsigned short f2h(float f) {
  __half h = __float2half(f);
  return *reinterpret_cast<unsigned short*>(&h);
}
__device__ __forceinline__ __half2 ash2(unsigned w) {
  return *reinterpret_cast<__half2*>(&w);
}

// ---------------- weight packing: 6 matrices (W1=top-bot x3, W2=bot x3) ----
__device__ __forceinline__ void pack_w_seg(const float* __restrict__ wq,
                                           const float* __restrict__ wk,
                                           const float* __restrict__ wv,
                                           unsigned short* __restrict__ dst,
                                           int IN, int O, float kscale, int id) {
  int kchunks = IN >> 5, nchunks = O >> 4;
  int total = 6 * nchunks * kchunks * 64;
  if (id >= total) return;
  int lane = id & 63;
  int frag = id >> 6;
  int kc = frag % kchunks;
  int nc = (frag / kchunks) % nchunks;
  int mat = frag / (kchunks * nchunks);
  const float* w = (mat % 3 == 0) ? wq : (mat % 3 == 1) ? wk : wv;
  float mul = (mat % 3 == 1) ? kscale : 1.0f;
  int n = nc * 16 + (lane & 15);
  int k0 = kc * 32 + (lane >> 4) * 8;
  unsigned short tmp[8];
#pragma unroll
  for (int j = 0; j < 8; ++j) {
    int row = k0 + j;
    float bot = w[(size_t)(IN + row) * O + n];
    float val = (mat < 3) ? (w[(size_t)row * O + n] - bot) : bot;
    tmp[j] = f2h(val * mul);
  }
  uint4 o;
  o.x = (unsigned)tmp[0] | ((unsigned)tmp[1] << 16);
  o.y = (unsigned)tmp[2] | ((unsigned)tmp[3] << 16);
  o.z = (unsigned)tmp[4] | ((unsigned)tmp[5] << 16);
  o.w = (unsigned)tmp[6] | ((unsigned)tmp[7] << 16);
  reinterpret_cast<uint4*>(dst)[id] = o;
}

__device__ __forceinline__ void pack_b_seg(const float* __restrict__ bq,
                                           const float* __restrict__ bk,
                                           const float* __restrict__ bv, float kscale, int O,
                                           float* __restrict__ out, int i) {
  int mat = i / O, c = i % O;
  float v = 0.f;
  if (mat == 0) v = bq[c];
  else if (mat == 1) v = bk[c] * kscale;
  else if (mat == 2) v = bv[c];
  out[i] = v;
}

// ---------------- fused preprocessing + edge histogram ----------------
// hist atomics (rank capture) + zeros (s0+s1, d_out) + weight/bias pack +
// x f32->fp16. hist must be zeroed BEFORE this kernel (hipMemsetAsync).
__global__ void preproc(
    const int* __restrict__ e0, const int* __restrict__ e1, const int* __restrict__ e2,
    int E, int* __restrict__ hist, int* __restrict__ rank, int NP,
    uint4* __restrict__ za, int na, uint4* __restrict__ zb, int nb,
    const float* __restrict__ x, unsigned short* __restrict__ xb, int n8,
    const float* __restrict__ wq0, const float* __restrict__ wk0, const float* __restrict__ wv0,
    const float* __restrict__ wq1, const float* __restrict__ wk1, const float* __restrict__ wv1,
    const float* __restrict__ wq2, const float* __restrict__ wk2, const float* __restrict__ wv2,
    unsigned short* __restrict__ wp0, unsigned short* __restrict__ wp1,
    unsigned short* __restrict__ wp2,
    const float* __restrict__ bq0, const float* __restrict__ bk0, const float* __restrict__ bv0,
    const float* __restrict__ bq1, const float* __restrict__ bk1, const float* __restrict__ bv1,
    const float* __restrict__ bq2, const float* __restrict__ bk2, const float* __restrict__ bv2,
    float* __restrict__ bias0, float* __restrict__ bias1, float* __restrict__ bias2,
    float sc16, float sc8) {
  const int tid = blockIdx.x * blockDim.x + threadIdx.x;
  const int stride = gridDim.x * blockDim.x;

  // edge histogram + rank (atomic returns); latency hides under streaming below
  for (int i = tid; i < E; i += stride) {
    rank[i] = atomicAdd(&hist[e0[E + i]], 1);
    rank[(size_t)E + i] = atomicAdd(&hist[NP + e1[E + i]], 1);
    rank[2 * (size_t)E + i] = atomicAdd(&hist[2 * NP + e2[E + i]], 1);
  }

  const uint4 Z = make_uint4(0u, 0u, 0u, 0u);
  for (int j = tid; j < na; j += stride) za[j] = Z;
  for (int j = tid; j < nb; j += stride) zb[j] = Z;
  for (int j = tid; j < n8; j += stride) {
    float4 a = reinterpret_cast<const float4*>(x)[2 * j];
    float4 b = reinterpret_cast<const float4*>(x)[2 * j + 1];
    uint4 o;
    o.x = (unsigned)f2h(a.x) | ((unsigned)f2h(a.y) << 16);
    o.y = (unsigned)f2h(a.z) | ((unsigned)f2h(a.w) << 16);
    o.z = (unsigned)f2h(b.x) | ((unsigned)f2h(b.y) << 16);
    o.w = (unsigned)f2h(b.z) | ((unsigned)f2h(b.w) << 16);
    reinterpret_cast<uint4*>(xb)[j] = o;
  }
  if (tid < 12288) pack_w_seg(wq0, wk0, wv0, wp0, 128, 128, sc16, tid);
  else if (tid < 18432) pack_w_seg(wq1, wk1, wv1, wp1, 128, 64, sc8, tid - 12288);
  else if (tid < 24576) pack_w_seg(wq2, wk2, wv2, wp2, 64, 128, sc16, tid - 18432);
  else if (tid < 24576 + 1920) {
    int i = tid - 24576;
    if (i < 768) pack_b_seg(bq0, bk0, bv0, sc16, 128, bias0, i);
    else if (i < 1152) pack_b_seg(bq1, bk1, bv1, sc8, 64, bias1, i - 768);
    else pack_b_seg(bq2, bk2, bv2, sc16, 128, bias2, i - 1152);
  }
}

// ---------------- scans ----------------
__device__ __forceinline__ int block_scan_excl256(int v, int* buf, int t, int* total) {
  buf[t] = v;
  __syncthreads();
#pragma unroll
  for (int off = 1; off < 256; off <<= 1) {
    int add = (t >= off) ? buf[t - off] : 0;
    __syncthreads();
    buf[t] += add;
    __syncthreads();
  }
  int incl = buf[t];
  *total = buf[255];
  __syncthreads();
  return incl - v;
}

__global__ void scan_pass1(const int* __restrict__ hist, int* __restrict__ excl,
                           int* __restrict__ bsum, int n, int NP) {
  __shared__ int buf[256];
  int y = blockIdx.y, t = threadIdx.x;
  int i = blockIdx.x * 256 + t;
  int v = (i < n) ? hist[y * NP + i] : 0;
  int total;
  int ex = block_scan_excl256(v, buf, t, &total);
  if (i < NP) excl[y * NP + i] = ex;
  if (t == 0) bsum[y * 256 + blockIdx.x] = total;
}

__global__ void scan_pass2(int* __restrict__ bsum, int nblk) {
  __shared__ int buf[256];
  int y = blockIdx.y, t = threadIdx.x;
  int v = (t < nblk) ? bsum[y * 256 + t] : 0;
  int total;
  int ex = block_scan_excl256(v, buf, t, &total);
  bsum[y * 256 + t] = ex;
}

__global__ void scan_pass3(const int* __restrict__ excl, const int* __restrict__ bsum,
                           int* __restrict__ rowptr, int n, int NP, int RP, int E) {
  int y = blockIdx.y;
  int i = blockIdx.x * 256 + threadIdx.x;
  if (i < n) rowptr[y * RP + i] = excl[y * NP + i] + bsum[y * 256 + blockIdx.x];
  if (i == 0) rowptr[y * RP + n] = E;
}

// scatter: pos = rowptr[d] + rank (no atomics); nontemporal 8B store
__global__ void scatter3(const int* __restrict__ e0, const int* __restrict__ e1,
                         const int* __restrict__ e2, int E, const int* __restrict__ rowptr,
                         const int* __restrict__ rank, long long* __restrict__ pairs,
                         int NP, int RP) {
  int y = blockIdx.y;
  const int* e = (y == 0) ? e0 : (y == 1) ? e1 : e2;
  int i = blockIdx.x * 256 + threadIdx.x;
  if (i >= E) return;
  int sN = e[i], d = e[E + i];
  int pos = rowptr[y * RP + d] + rank[(size_t)y * E + i];
  long long val = ((long long)(unsigned)d << 32) | (unsigned)sN;  // x=sN, y=d
  __builtin_nontemporal_store(val, &pairs[(size_t)y * E + pos]);
}

// ---------------- node-level GEMM (fp16 MFMA) ----------------
// 1-D padded grid, bijective XCD swizzle; logical lb -> (tile = lb/G, grp = lb%G)
template <int IN, int O, int G>
__global__ __launch_bounds__(256, 4) void node_gemm(
    const unsigned short* __restrict__ xb, int N, int NT,
    const unsigned short* __restrict__ wpack, const float* __restrict__ bias6,
    unsigned short* __restrict__ Y1, unsigned short* __restrict__ Y2) {
  constexpr int KC = IN / 32;
  constexpr int NCH = O / 16;
  constexpr int CHR = IN / 8;
  constexpr int CM = CHR - 1;
  __shared__ unsigned short tiles[64 * IN];

  const int chunk = gridDim.x >> 3;  // grid is a multiple of 8
  const int lb = (blockIdx.x & 7) * chunk + (blockIdx.x >> 3);
  if (lb >= NT * G) return;
  const int tile = lb / G;
  const int grp = lb % G;

  const int t = threadIdx.x, w = t >> 6, ln = t & 63;
  const int n0 = tile * 64;

  {
    constexpr int RPI = 64 / CHR;
    constexpr int NI = 16 / RPI;
    const int r_in = ln / CHR, c = ln % CHR;
#pragma unroll
    for (int i = 0; i < NI; ++i) {
      int row = w * 16 + i * RPI + r_in;
      int node = min(n0 + row, N - 1);
      int sc = c ^ (row & CM);
      const unsigned short* g = xb + (size_t)node * IN + sc * 8;
      unsigned short* l = &tiles[(size_t)(w * 16 + i * RPI) * IN];
      __builtin_amdgcn_global_load_lds(
          (const __attribute__((address_space(1))) unsigned int*)g,
          (__attribute__((address_space(3))) unsigned int*)l, 16, 0, 0);
    }
  }
  __syncthreads();

  const int col = ln & 15, quad = ln >> 4;
  const int g0 = grp * 8 + w * 2;

  f32x4 acc[2][4];
#pragma unroll
  for (int cc = 0; cc < 2; ++cc)
#pragma unroll
    for (int m = 0; m < 4; ++m) acc[cc][m] = (f32x4){0.f, 0.f, 0.f, 0.f};

#pragma unroll
  for (int kc = 0; kc < KC; ++kc) {
    f16x8 a[4];
#pragma unroll
    for (int m = 0; m < 4; ++m) {
      int row = m * 16 + col;
      int sc = (kc * 4 + quad) ^ (row & CM);
      a[m] = *reinterpret_cast<const f16x8*>(&tiles[(size_t)row * IN + sc * 8]);
    }
#pragma unroll
    for (int cc = 0; cc < 2; ++cc) {
      const f16x8 b = *reinterpret_cast<const f16x8*>(
          wpack + ((size_t)((g0 + cc) * KC + kc) * 64 + ln) * 8);
#pragma unroll
      for (int m = 0; m < 4; ++m)
        acc[cc][m] = __builtin_amdgcn_mfma_f32_16x16x32_f16(a[m], b, acc[cc][m], 0, 0, 0);
    }
  }

#pragma unroll
  for (int cc = 0; cc < 2; ++cc) {
    int gch = g0 + cc;
    int mat = gch / NCH, ncg = gch % NCH;
    unsigned short* Yp = (mat < 3) ? Y1 : Y2;
    int mo = (mat < 3) ? mat : mat - 3;
    float bv = bias6[gch * 16 + col];
    size_t coloff = (size_t)mo * O + ncg * 16 + col;
#pragma unroll
    for (int m = 0; m < 4; ++m)
#pragma unroll
      for (int r = 0; r < 4; ++r) {
        int node = n0 + m * 16 + quad * 4 + r;
        if (node < N) Yp[(size_t)node * (3 * O) + coloff] = f2h(acc[cc][m][r] + bv);
      }
  }
}

// ---------------- gather-based edge kernel (packed fp16 math) ----------------
// 512 threads, 64 edges, 8 threads/edge, thread = one head (HS channels).
template <int O, int HS>
__global__ __launch_bounds__(512, 6) void edge_attn_kernel(
    const unsigned short* __restrict__ Y1, const unsigned short* __restrict__ Y2,
    const int2* __restrict__ pairs, const int E, float* __restrict__ s) {
  constexpr int NL = HS / 8;
  constexpr int PM = O / 4 - 1;
  __shared__ float ctx[64 * O];
  __shared__ int dstL[64];

  const int chunkB = gridDim.x >> 3;
  const int lb = (blockIdx.x & 7) * chunkB + (blockIdx.x >> 3);
  if (lb * 64 >= E) return;

  const int t = threadIdx.x;
  const int e = t >> 3, head = t & 7;
  const int eG = lb * 64 + e;
  const int eC = min(eG, E - 1);
  const bool valid = eG < E;
  const int2 p = pairs[eC];
  const int sN = p.x, dN = p.y;
  if ((t & 7) == 0) dstL[e] = dN;
  const float dd = fabsf((float)(dN - sN));
  const float ew = (dd > 8.f) ? 1.f : ((dd == 8.f) ? 0.f : -1.f);

  const unsigned short* b1 = Y1 + (size_t)dN * (3 * O) + head * HS;
  const unsigned short* b2 = Y2 + (size_t)sN * (3 * O) + head * HS;

  u32x4 q1[NL], q2[NL], k1[NL], k2[NL], v1[NL], v2[NL];
#pragma unroll
  for (int l = 0; l < NL; ++l) {
    q1[l] = *reinterpret_cast<const u32x4*>(b1 + l * 8);
    q2[l] = *reinterpret_cast<const u32x4*>(b2 + l * 8);
    k1[l] = *reinterpret_cast<const u32x4*>(b1 + O + l * 8);
    k2[l] = *reinterpret_cast<const u32x4*>(b2 + O + l * 8);
    v1[l] = *reinterpret_cast<const u32x4*>(b1 + 2 * O + l * 8);
    v2[l] = *reinterpret_cast<const u32x4*>(b2 + 2 * O + l * 8);
  }

  f32x2 ex2[NL * 4];
  f32x2 sum2 = (f32x2){0.f, 0.f};
#pragma unroll
  for (int l = 0; l < NL; ++l)
#pragma unroll
    for (int d = 0; d < 4; ++d) {
      __half2 qh = __hadd2(ash2(q1[l][d]), ash2(q2[l][d]));
      __half2 kh = __hadd2(ash2(k1[l][d]), ash2(k2[l][d]));
      __half2 qk = __hmul2(qh, kh);  // log2e*scale already folded into k
      f32x2 eo;
      eo.x = exp2f(__low2float(qk));
      eo.y = exp2f(__high2float(qk));
      ex2[l * 4 + d] = eo;
      sum2 += eo;
    }
  const float sum = sum2.x + sum2.y;
  const float rs = valid ? (ew / sum) : 0.f;
  const f32x2 rs2 = (f32x2){rs, rs};
#pragma unroll
  for (int l = 0; l < NL; ++l) {
#pragma unroll
    for (int g2 = 0; g2 < 2; ++g2) {
      __half2 va = __hadd2(ash2(v1[l][g2 * 2]), ash2(v2[l][g2 * 2]));
      __half2 vb = __hadd2(ash2(v1[l][g2 * 2 + 1]), ash2(v2[l][g2 * 2 + 1]));
      f32x2 vva = (f32x2){__low2float(va), __high2float(va)};
      f32x2 vvb = (f32x2){__low2float(vb), __high2float(vb)};
      f32x2 oa = ex2[l * 4 + g2 * 2] * rs2 * vva;
      f32x2 ob = ex2[l * 4 + g2 * 2 + 1] * rs2 * vvb;
      f32x4 o = (f32x4){oa.x, oa.y, ob.x, ob.y};
      int g = l * 2 + g2;
      int pch = (g * 8 + head + e) & PM;
      *reinterpret_cast<f32x4*>(&ctx[e * O + pch * 4]) = o;
    }
  }
  __syncthreads();

  {
    constexpr int GRP = 512 / O;
    constexpr int EPT = 64 / GRP;
    const int hs2 = t & 7;
    const int cs = (t >> 3) & (HS - 1);
    const int colA = hs2 * HS + cs;
    const int seg0 = (t / O) * EPT;
    const int inv = (cs >> 2) * 8 + hs2;
    const int js = cs & 3;
    float run = 0.f;
    int runstart = 0;           // i where current run began (0 => may predate segment)
    int dcur = dstL[seg0];
#pragma unroll
    for (int i = 0; i < EPT; ++i) {
      int ee = seg0 + i;
      int pch = (inv + ee) & PM;
      run += ctx[ee * O + pch * 4 + js];
      int dnext = (i < EPT - 1) ? dstL[ee + 1] : -1;
      if (dnext != dcur) {
        float* addr = &s[(size_t)dcur * O + colA];
        // run fully contained in this thread's segment -> exclusive -> plain store
        if (runstart > 0 && i < EPT - 1) *addr = run;
        else atomicAdd(addr, run);
        run = 0.f;
        runstart = i + 1;
        dcur = dnext;
      }
    }
  }
}

// ---------------- finalize ----------------
__global__ void finalize_relu_f32h(float* __restrict__ s, const int* __restrict__ rowptr,
                                   unsigned short* __restrict__ xbo, int total4, int Odiv4) {
  int i = blockIdx.x * blockDim.x + threadIdx.x;
  if (i >= total4) return;
  int node = i / Odiv4;
  float c = fmaxf((float)(rowptr[node + 1] - rowptr[node]), 1.0f);
  float4 v = reinterpret_cast<float4*>(s)[i];
  v.x = fmaxf(v.x / c, 0.f);
  v.y = fmaxf(v.y / c, 0.f);
  v.z = fmaxf(v.z / c, 0.f);
  v.w = fmaxf(v.w / c, 0.f);
  reinterpret_cast<float4*>(s)[i] = v;
  ushort4 o = make_ushort4(f2h(v.x), f2h(v.y), f2h(v.z), f2h(v.w));
  reinterpret_cast<ushort4*>(xbo)[i] = o;
}

__global__ void finalize_relu_h(const float* __restrict__ s, const int* __restrict__ rowptr,
                                unsigned short* __restrict__ xbo, int total4, int Odiv4) {
  int i = blockIdx.x * blockDim.x + threadIdx.x;
  if (i >= total4) return;
  int node = i / Odiv4;
  float c = fmaxf((float)(rowptr[node + 1] - rowptr[node]), 1.0f);
  float4 v = reinterpret_cast<const float4*>(s)[i];
  ushort4 o = make_ushort4(f2h(fmaxf(v.x / c, 0.f)), f2h(fmaxf(v.y / c, 0.f)),
                           f2h(fmaxf(v.z / c, 0.f)), f2h(fmaxf(v.w / c, 0.f)));
  reinterpret_cast<ushort4*>(xbo)[i] = o;
}

__global__ void finalize_add_relu(float* __restrict__ out, const float* __restrict__ x0,
                                  const int* __restrict__ rowptr, int total4, int Odiv4) {
  int i = blockIdx.x * blockDim.x + threadIdx.x;
  if (i >= total4) return;
  int node = i / Odiv4;
  float c = fmaxf((float)(rowptr[node + 1] - rowptr[node]), 1.0f);
  float4 v = reinterpret_cast<float4*>(out)[i];
  float4 r = reinterpret_cast<const float4*>(x0)[i];
  v.x = fmaxf(v.x / c + r.x, 0.f);
  v.y = fmaxf(v.y / c + r.y, 0.f);
  v.z = fmaxf(v.z / c + r.z, 0.f);
  v.w = fmaxf(v.w / c + r.w, 0.f);
  reinterpret_cast<float4*>(out)[i] = v;
}

extern "C" void kernel_launch(void* const* d_in, const int* in_sizes, int n_in,
                              void* d_out, int out_size, void* d_ws, size_t ws_size,
                              hipStream_t stream) {
  const float* x = (const float*)d_in[0];
  const int* e0 = (const int*)d_in[1];
  const int* e1 = (const int*)d_in[2];
  const int* e2 = (const int*)d_in[3];
  const float* wq0 = (const float*)d_in[5];
  const float* bq0 = (const float*)d_in[6];
  const float* wk0 = (const float*)d_in[7];
  const float* bk0 = (const float*)d_in[8];
  const float* wv0 = (const float*)d_in[9];
  const float* bv0 = (const float*)d_in[10];
  const float* wq1 = (const float*)d_in[11];
  const float* bq1 = (const float*)d_in[12];
  const float* wk1 = (const float*)d_in[13];
  const float* bk1 = (const float*)d_in[14];
  const float* wv1 = (const float*)d_in[15];
  const float* bv1 = (const float*)d_in[16];
  const float* wq2 = (const float*)d_in[17];
  const float* bq2 = (const float*)d_in[18];
  const float* wk2 = (const float*)d_in[19];
  const float* bk2 = (const float*)d_in[20];
  const float* wv2 = (const float*)d_in[21];
  const float* bv2 = (const float*)d_in[22];

  const int N = in_sizes[0] / 128;  // 50000
  const int E = in_sizes[1] / 2;    // 500000
  const int NBLK = (N + 255) / 256;
  const int NP = NBLK * 256;
  const int RP = NP + 256;
  const float LOG2E = 1.4426950408889634f;
  const float SC16 = 0.25f * LOG2E;                 // 1/sqrt(16) * log2e
  const float SC8 = 0.35355339059327373f * LOG2E;   // 1/sqrt(8)  * log2e

  // ---- workspace carve-up ----
  unsigned short* wp0 = (unsigned short*)d_ws;       // 98304 shorts
  unsigned short* wp1 = wp0 + 98304;                 // 49152
  unsigned short* wp2 = wp1 + 49152;                 // 49152
  float* bias0 = (float*)(wp2 + 49152);              // 768
  float* bias1 = bias0 + 768;                        // 384
  float* bias2 = bias1 + 384;                        // 768
  unsigned short* xb = (unsigned short*)(bias2 + 768);  // N*128
  unsigned short* Y1 = xb + (size_t)N * 128;         // N*384
  unsigned short* Y2 = Y1 + (size_t)N * 384;         // N*384
  float* s0 = (float*)(Y2 + (size_t)N * 384);        // N*128
  float* s1 = s0 + (size_t)N * 128;                  // N*64
  int* hist = (int*)(s1 + (size_t)N * 64);           // 3*NP
  int* excl = hist + 3 * (size_t)NP;                 // 3*NP
  int* bsum = excl + 3 * (size_t)NP;                 // 768
  int* rowptr = bsum + 768;                          // 3*RP
  int* rank = rowptr + 3 * (size_t)RP;               // 3*E
  long long* pairs = (long long*)(rank + 3 * (size_t)E + 2);  // 3*E (8B aligned)

  hipMemsetAsync(hist, 0, 3 * (size_t)NP * sizeof(int), stream);

  // fused preprocessing: hist atomics + zeros + weight/bias pack + x->fp16
  preproc<<<2048, 256, 0, stream>>>(
      e0, e1, e2, E, hist, rank, NP,
      (uint4*)s0, N * 48, (uint4*)d_out, out_size / 4,
      x, xb, N * 16,
      wq0, wk0, wv0, wq1, wk1, wv1, wq2, wk2, wv2, wp0, wp1, wp2,
      bq0, bk0, bv0, bq1, bk1, bv1, bq2, bk2, bv2, bias0, bias1, bias2,
      SC16, SC8);

  scan_pass1<<<dim3(NBLK, 3), 256, 0, stream>>>(hist, excl, bsum, N, NP);
  scan_pass2<<<dim3(1, 3), 256, 0, stream>>>(bsum, NBLK);
  scan_pass3<<<dim3(NBLK, 3), 256, 0, stream>>>(excl, bsum, rowptr, N, NP, RP, E);

  const int EB256 = (E + 255) / 256;
  scatter3<<<dim3(EB256, 3), 256, 0, stream>>>(e0, e1, e2, E, rowptr, rank, pairs, NP, RP);

  const int NT = (N + 63) / 64;
  const int EBK = (E + 63) / 64;
  const int EGRID = 8 * ((EBK + 7) / 8);  // bijective XCD swizzle grid
  const int GG6 = 8 * ((NT * 6 + 7) / 8);
  const int GG3 = 8 * ((NT * 3 + 7) / 8);

  // Layer 0: IN=128, O=128, HS=16
  node_gemm<128, 128, 6><<<GG6, 256, 0, stream>>>(xb, N, NT, wp0, bias0, Y1, Y2);
  edge_attn_kernel<128, 16><<<EGRID, 512, 0, stream>>>(Y1, Y2, (const int2*)pairs, E, s0);
  finalize_relu_f32h<<<(N * 32 + 255) / 256, 256, 0, stream>>>(s0, rowptr, xb, N * 32, 32);
  // Layer 1: IN=128, O=64, HS=8
  node_gemm<128, 64, 3><<<GG3, 256, 0, stream>>>(xb, N, NT, wp1, bias1, Y1, Y2);
  edge_attn_kernel<64, 8><<<EGRID, 512, 0, stream>>>(Y1, Y2, (const int2*)(pairs + E), E, s1);
  finalize_relu_h<<<(N * 16 + 255) / 256, 256, 0, stream>>>(s1, rowptr + RP, xb, N * 16, 16);
  // Layer 2: IN=64, O=128, HS=16 -> accumulate into d_out
  node_gemm<64, 128, 6><<<GG6, 256, 0, stream>>>(xb, N, NT, wp2, bias2, Y1, Y2);
  edge_attn_kernel<128, 16><<<EGRID, 512, 0, stream>>>(Y1, Y2, (const int2*)(pairs + 2 * (size_t)E),
                                                       E, (float*)d_out);
  finalize_add_relu<<<(N * 32 + 255) / 256, 256, 0, stream>>>((float*)d_out, s0, rowptr + 2 * RP,
                                                              N * 32, 32);
}